// Round 1
// baseline (1924.745 us; speedup 1.0000x reference)
//
#include <hip/hip_runtime.h>

#define NPTS 65536
#define DIM  512
#define HID  256
#define KCL  16
#define NLVL 3
#define NCLS 64
#define NSEG (NCLS*KCL)
#define EPSF 1e-5f

// ============================ assign: h=relu(xW1+b1); logits=hW2+b2; argmax ============
// block: 64 rows x 256 cols of h. threads 256 = (tx 16, ty 16).
// thread computes rows r=ty*4..+3, cols j in {4tx + 64q + m}.
__global__ __launch_bounds__(256, 2) void assign_kernel(
    const float* __restrict__ feat, const int* __restrict__ labels,
    const float* __restrict__ off,
    const float* __restrict__ w1, const float* __restrict__ pb1,
    const float* __restrict__ w2, const float* __restrict__ pb2,
    int* __restrict__ asg, int* __restrict__ cnt)
{
  __shared__ float At[32*68];     // A^T chunk [k][r], stride 68 (16B-aligned rows, conflict-broken)
  __shared__ float Wc[32*256];    // W1 chunk [k][j]
  __shared__ float W2s[256*21];   // W2 [j][kk], stride 21
  __shared__ float b1s[256];
  __shared__ int   labs[64];

  const int tid = threadIdx.x;
  const int tx = tid & 15, ty = tid >> 4;
  const int row0 = blockIdx.x * 64;

  if (tid < 64) labs[tid] = labels[row0 + tid];
  b1s[tid] = pb1[tid];
  for (int idx = tid; idx < HID*KCL; idx += 256)
    W2s[(idx >> 4)*21 + (idx & 15)] = w2[idx];

  float acc[4][16];
  #pragma unroll
  for (int i = 0; i < 4; i++)
    #pragma unroll
    for (int q = 0; q < 16; q++) acc[i][q] = 0.f;

  const int kkk = tid & 31, rb = tid >> 5;

  for (int kc = 0; kc < DIM; kc += 32) {
    __syncthreads();
    #pragma unroll
    for (int p = 0; p < 8; p++) {
      int r = rb + 8*p;
      At[kkk*68 + r] = feat[(size_t)(row0 + r)*DIM + kc + kkk]
                     + off[(size_t)labs[r]*DIM + kc + kkk];
    }
    #pragma unroll
    for (int p = 0; p < 8; p++) {
      int idx4 = tid + 256*p;           // 0..2047
      int kr = idx4 >> 6;               // 0..31
      int jv = (idx4 & 63) << 2;        // 0..252
      *(float4*)&Wc[kr*256 + jv] = *(const float4*)&w1[(size_t)(kc + kr)*HID + jv];
    }
    __syncthreads();
    #pragma unroll
    for (int k = 0; k < 32; k++) {
      float4 a4  = *(const float4*)&At[k*68 + ty*4];
      float4 q0  = *(const float4*)&Wc[k*256 + tx*4];
      float4 q1  = *(const float4*)&Wc[k*256 + tx*4 + 64];
      float4 q2  = *(const float4*)&Wc[k*256 + tx*4 + 128];
      float4 q3  = *(const float4*)&Wc[k*256 + tx*4 + 192];
      float av[4] = {a4.x, a4.y, a4.z, a4.w};
      float bv[16] = {q0.x,q0.y,q0.z,q0.w, q1.x,q1.y,q1.z,q1.w,
                      q2.x,q2.y,q2.z,q2.w, q3.x,q3.y,q3.z,q3.w};
      #pragma unroll
      for (int i = 0; i < 4; i++)
        #pragma unroll
        for (int q = 0; q < 16; q++)
          acc[i][q] = fmaf(av[i], bv[q], acc[i][q]);
    }
  }

  // bias + relu (h now lives in acc)
  #pragma unroll
  for (int i = 0; i < 4; i++)
    #pragma unroll
    for (int q = 0; q < 16; q++) {
      int j = ((q >> 2) << 6) + tx*4 + (q & 3);
      acc[i][q] = fmaxf(acc[i][q] + b1s[j], 0.f);
    }

  // logits partials over this thread's 16 j-columns
  float part[4][16];
  #pragma unroll
  for (int i = 0; i < 4; i++)
    #pragma unroll
    for (int k2 = 0; k2 < 16; k2++) part[i][k2] = 0.f;

  #pragma unroll
  for (int q = 0; q < 16; q++) {
    int j = ((q >> 2) << 6) + tx*4 + (q & 3);
    float w2r[16];
    #pragma unroll
    for (int s = 0; s < 16; s++) w2r[s] = W2s[j*21 + s];
    #pragma unroll
    for (int i = 0; i < 4; i++)
      #pragma unroll
      for (int k2 = 0; k2 < 16; k2++)
        part[i][k2] = fmaf(acc[i][q], w2r[k2], part[i][k2]);
  }

  // reduce across the 16 tx lanes (contiguous within wave)
  #pragma unroll
  for (int ofs = 8; ofs > 0; ofs >>= 1)
    #pragma unroll
    for (int i = 0; i < 4; i++)
      #pragma unroll
      for (int k2 = 0; k2 < 16; k2++)
        part[i][k2] += __shfl_xor(part[i][k2], ofs, 16);

  if (tx == 0) {
    #pragma unroll
    for (int i = 0; i < 4; i++) {
      int r = ty*4 + i;
      float best = part[i][0] + pb2[0];
      int bi = 0;
      #pragma unroll
      for (int k2 = 1; k2 < 16; k2++) {
        float v = part[i][k2] + pb2[k2];
        if (v > best) { best = v; bi = k2; }   // strict > keeps first max (jnp.argmax)
      }
      asg[row0 + r] = bi;
      atomicAdd(&cnt[labs[r]*KCL + bi], 1);
    }
  }
}

// ============================ exclusive scan of segment counts ============================
__global__ void scan_kernel(const int* __restrict__ cnt, int* __restrict__ seg_st,
                            int* __restrict__ cursor)
{
  __shared__ int sc[NSEG];
  int t = threadIdx.x;
  sc[t] = cnt[t];
  __syncthreads();
  for (int ofs = 1; ofs < NSEG; ofs <<= 1) {
    int v = (t >= ofs) ? sc[t - ofs] : 0;
    __syncthreads();
    sc[t] += v;
    __syncthreads();
  }
  seg_st[t + 1] = sc[t];
  if (t == 0) seg_st[0] = 0;
  cursor[t] = sc[t] - cnt[t];
}

// ============================ scatter rows into per-segment lists =========================
__global__ __launch_bounds__(256) void scatter_kernel(
    const int* __restrict__ labels, const int* __restrict__ asg,
    int* __restrict__ cursor, int* __restrict__ rowlist)
{
  int i = blockIdx.x * 256 + threadIdx.x;
  int seg = labels[i]*KCL + asg[i];
  int pos = atomicAdd(&cursor[seg], 1);
  rowlist[pos] = i;
}

// ============================ per-segment means ===========================================
// means[seg] = mean(feat rows) + off[class]   (== segsum(feat+off)/cnt)
__global__ __launch_bounds__(256) void means_kernel(
    const float* __restrict__ feat, const float* __restrict__ off,
    const int* __restrict__ rowlist, const int* __restrict__ seg_st,
    float* __restrict__ means)
{
  int seg = blockIdx.x;
  int c = seg >> 4;
  int s = seg_st[seg], e = seg_st[seg + 1];
  int t = threadIdx.x;
  float s0 = 0.f, s1 = 0.f;
  for (int i = s; i < e; i++) {
    const float* fr = feat + (size_t)rowlist[i]*DIM;
    s0 += fr[t];
    s1 += fr[t + 256];
  }
  float n = (float)(e - s);
  float inv = 1.f / fmaxf(n, 1.f);
  means[(size_t)seg*DIM + t]       = (s0 + n*off[c*DIM + t]) * inv;
  means[(size_t)seg*DIM + t + 256] = (s1 + n*off[c*DIM + t + 256]) * inv;
}

// ============================ refiner: Linear->LN->ReLU->Linear, masked class-mean ========
// block: 8 segment rows (all same class). threads own cols {t, t+256}.
__global__ __launch_bounds__(256, 2) void refine_kernel(
    const float* __restrict__ means, const int* __restrict__ cnt,
    const float* __restrict__ w1, const float* __restrict__ pb1,
    const float* __restrict__ g, const float* __restrict__ bgb,
    const float* __restrict__ w2, const float* __restrict__ pb2,
    float* __restrict__ lp_sum)
{
  __shared__ float Ah[8*512];     // means rows, later h
  __shared__ float Wc[16*512];
  __shared__ float red[2][8][4];
  __shared__ float mS[8], rS[8];

  int t = threadIdx.x;
  int seg0 = blockIdx.x * 8;
  int c = seg0 >> 4;

  #pragma unroll
  for (int p = 0; p < 16; p++) {
    int idx = t + 256*p;
    Ah[idx] = means[(size_t)seg0*DIM + idx];
  }

  float acc[8][2];
  #pragma unroll
  for (int r = 0; r < 8; r++) { acc[r][0] = 0.f; acc[r][1] = 0.f; }

  for (int kc = 0; kc < DIM; kc += 16) {
    __syncthreads();
    #pragma unroll
    for (int p = 0; p < 8; p++) {
      int idx4 = t + 256*p;                    // 0..2047
      int kr = idx4 >> 7;                      // 0..15
      int jv = (idx4 & 127) << 2;              // 0..508
      *(float4*)&Wc[kr*512 + jv] = *(const float4*)&w1[(size_t)(kc + kr)*DIM + jv];
    }
    __syncthreads();
    #pragma unroll
    for (int k = 0; k < 16; k++) {
      float w0 = Wc[k*512 + t];
      float w1v = Wc[k*512 + t + 256];
      #pragma unroll
      for (int r = 0; r < 8; r++) {
        float a = Ah[r*512 + kc + k];
        acc[r][0] = fmaf(a, w0, acc[r][0]);
        acc[r][1] = fmaf(a, w1v, acc[r][1]);
      }
    }
  }
  __syncthreads();   // all reads of Ah(means) done

  // t-vals = acc + b1 ; write to Ah and compute LN stats from registers
  float v0r[8], v1r[8];
  float tb0 = pb1[t], tb1 = pb1[t + 256];
  #pragma unroll
  for (int r = 0; r < 8; r++) {
    v0r[r] = acc[r][0] + tb0;
    v1r[r] = acc[r][1] + tb1;
    Ah[r*512 + t] = v0r[r];
    Ah[r*512 + t + 256] = v1r[r];
  }
  float s1v[8], s2v[8];
  #pragma unroll
  for (int r = 0; r < 8; r++) {
    s1v[r] = v0r[r] + v1r[r];
    s2v[r] = v0r[r]*v0r[r] + v1r[r]*v1r[r];
  }
  int lane = t & 63, wv = t >> 6;
  #pragma unroll
  for (int ofs = 32; ofs > 0; ofs >>= 1)
    #pragma unroll
    for (int r = 0; r < 8; r++) {
      s1v[r] += __shfl_down(s1v[r], ofs);
      s2v[r] += __shfl_down(s2v[r], ofs);
    }
  if (lane == 0)
    #pragma unroll
    for (int r = 0; r < 8; r++) { red[0][r][wv] = s1v[r]; red[1][r][wv] = s2v[r]; }
  __syncthreads();
  if (t < 8) {
    float a = 0.f, b = 0.f;
    #pragma unroll
    for (int w = 0; w < 4; w++) { a += red[0][t][w]; b += red[1][t][w]; }
    float m = a * (1.f/512.f);
    float var = b * (1.f/512.f) - m*m;
    mS[t] = m;
    rS[t] = rsqrtf(var + EPSF);
  }
  __syncthreads();

  // LN + relu in place
  float g0 = g[t], g1 = g[t + 256], bb0 = bgb[t], bb1 = bgb[t + 256];
  #pragma unroll
  for (int r = 0; r < 8; r++) {
    float m = mS[r], rs = rS[r];
    float x0 = fmaxf((Ah[r*512 + t] - m) * rs * g0 + bb0, 0.f);
    float x1 = fmaxf((Ah[r*512 + t + 256] - m) * rs * g1 + bb1, 0.f);
    Ah[r*512 + t] = x0;
    Ah[r*512 + t + 256] = x1;
  }
  __syncthreads();

  // GEMM2: refined = h @ w2 + b2
  float acc2[8][2];
  #pragma unroll
  for (int r = 0; r < 8; r++) { acc2[r][0] = 0.f; acc2[r][1] = 0.f; }
  for (int kc = 0; kc < DIM; kc += 16) {
    __syncthreads();
    #pragma unroll
    for (int p = 0; p < 8; p++) {
      int idx4 = t + 256*p;
      int kr = idx4 >> 7;
      int jv = (idx4 & 127) << 2;
      *(float4*)&Wc[kr*512 + jv] = *(const float4*)&w2[(size_t)(kc + kr)*DIM + jv];
    }
    __syncthreads();
    #pragma unroll
    for (int k = 0; k < 16; k++) {
      float w0 = Wc[k*512 + t];
      float w1v = Wc[k*512 + t + 256];
      #pragma unroll
      for (int r = 0; r < 8; r++) {
        float a = Ah[r*512 + kc + k];
        acc2[r][0] = fmaf(a, w0, acc2[r][0]);
        acc2[r][1] = fmaf(a, w1v, acc2[r][1]);
      }
    }
  }
  float ob0 = pb2[t], ob1 = pb2[t + 256];
  #pragma unroll
  for (int r = 0; r < 8; r++) {
    if (cnt[seg0 + r] > 0) {
      atomicAdd(&lp_sum[c*DIM + t],       acc2[r][0] + ob0);
      atomicAdd(&lp_sum[c*DIM + t + 256], acc2[r][1] + ob1);
    }
  }
}

// ============================ normalize lp, accumulate off ================================
__global__ __launch_bounds__(256) void lpnorm_kernel(
    const float* __restrict__ lp_sum, const int* __restrict__ cnt,
    float* __restrict__ off, float* __restrict__ lp_out)
{
  int gi = blockIdx.x * 256 + threadIdx.x;   // 0..32767
  int c = gi >> 9;
  int nes = 0;
  #pragma unroll
  for (int k = 0; k < KCL; k++) nes += (cnt[c*KCL + k] > 0);
  float lp = lp_sum[gi] / (float)nes;
  lp_out[gi] = lp;
  off[gi] += lp;
}

// ============================ final combiner ==============================================
__global__ __launch_bounds__(256) void final_kernel(
    const float* __restrict__ lp_all,
    const float* __restrict__ cw1, const float* __restrict__ cb1,
    const float* __restrict__ cw2, const float* __restrict__ cb2,
    float* __restrict__ out)
{
  __shared__ float comb[NLVL*DIM];
  __shared__ float Wc[16*512];
  __shared__ float Hs[512];
  int t = threadIdx.x;
  int c = blockIdx.x;

  #pragma unroll
  for (int p = 0; p < 6; p++) {
    int idx = t + 256*p;                  // 0..1535
    comb[idx] = lp_all[(size_t)(idx >> 9)*NCLS*DIM + (size_t)c*DIM + (idx & 511)];
  }

  float a0 = 0.f, a1 = 0.f;
  for (int kc = 0; kc < NLVL*DIM; kc += 16) {
    __syncthreads();
    #pragma unroll
    for (int p = 0; p < 8; p++) {
      int idx4 = t + 256*p;
      int kr = idx4 >> 7;
      int jv = (idx4 & 127) << 2;
      *(float4*)&Wc[kr*512 + jv] = *(const float4*)&cw1[(size_t)(kc + kr)*DIM + jv];
    }
    __syncthreads();
    #pragma unroll
    for (int k = 0; k < 16; k++) {
      float a = comb[kc + k];
      a0 = fmaf(a, Wc[k*512 + t], a0);
      a1 = fmaf(a, Wc[k*512 + t + 256], a1);
    }
  }
  Hs[t] = fmaxf(a0 + cb1[t], 0.f);
  Hs[t + 256] = fmaxf(a1 + cb1[t + 256], 0.f);

  a0 = 0.f; a1 = 0.f;
  for (int kc = 0; kc < DIM; kc += 16) {
    __syncthreads();
    #pragma unroll
    for (int p = 0; p < 8; p++) {
      int idx4 = t + 256*p;
      int kr = idx4 >> 7;
      int jv = (idx4 & 127) << 2;
      *(float4*)&Wc[kr*512 + jv] = *(const float4*)&cw2[(size_t)(kc + kr)*DIM + jv];
    }
    __syncthreads();
    #pragma unroll
    for (int k = 0; k < 16; k++) {
      float h = Hs[kc + k];
      a0 = fmaf(h, Wc[k*512 + t], a0);
      a1 = fmaf(h, Wc[k*512 + t + 256], a1);
    }
  }
  out[(size_t)c*DIM + t] = a0 + cb2[t];
  out[(size_t)c*DIM + t + 256] = a1 + cb2[t + 256];
}

// ============================ launch ======================================================
extern "C" void kernel_launch(void* const* d_in, const int* in_sizes, int n_in,
                              void* d_out, int out_size, void* d_ws, size_t ws_size,
                              hipStream_t stream) {
  const float* feat   = (const float*)d_in[0];
  const int*   labels = (const int*)d_in[1];
  const float* ch_w1  = (const float*)d_in[2];
  const float* ch_b1  = (const float*)d_in[3];
  const float* ch_w2  = (const float*)d_in[4];
  const float* ch_b2  = (const float*)d_in[5];
  const float* ref_w1 = (const float*)d_in[6];
  const float* ref_b1 = (const float*)d_in[7];
  const float* ln_g   = (const float*)d_in[8];
  const float* ln_b   = (const float*)d_in[9];
  const float* ref_w2 = (const float*)d_in[10];
  const float* ref_b2 = (const float*)d_in[11];
  const float* cw1    = (const float*)d_in[12];
  const float* cb1    = (const float*)d_in[13];
  const float* cw2    = (const float*)d_in[14];
  const float* cb2    = (const float*)d_in[15];
  float* out = (float*)d_out;

  float* wsf     = (float*)d_ws;
  float* off     = wsf;                         // 32768
  float* lp_sum  = wsf + 32768;                 // 32768
  float* lp_all  = wsf + 65536;                 // 98304
  float* means   = wsf + 163840;                // 524288
  int*   asg     = (int*)(wsf + 688128);        // 65536
  int*   rowlist = asg + NPTS;                  // 65536
  int*   cnt_i   = rowlist + NPTS;              // 1024
  int*   seg_st  = cnt_i + NSEG;                // 1025
  int*   cursor  = seg_st + NSEG + 4;           // 1024

  hipMemsetAsync(off, 0, NCLS*DIM*sizeof(float), stream);

  for (int l = 0; l < NLVL; l++) {
    hipMemsetAsync(cnt_i, 0, NSEG*sizeof(int), stream);
    hipMemsetAsync(lp_sum, 0, NCLS*DIM*sizeof(float), stream);

    assign_kernel<<<NPTS/64, 256, 0, stream>>>(
        feat, labels, off,
        ch_w1 + (size_t)l*DIM*HID, ch_b1 + (size_t)l*HID,
        ch_w2 + (size_t)l*HID*KCL, ch_b2 + (size_t)l*KCL,
        asg, cnt_i);

    scan_kernel<<<1, NSEG, 0, stream>>>(cnt_i, seg_st, cursor);

    scatter_kernel<<<NPTS/256, 256, 0, stream>>>(labels, asg, cursor, rowlist);

    means_kernel<<<NSEG, 256, 0, stream>>>(feat, off, rowlist, seg_st, means);

    refine_kernel<<<NSEG/8, 256, 0, stream>>>(
        means, cnt_i,
        ref_w1 + (size_t)l*DIM*DIM, ref_b1 + (size_t)l*DIM,
        ln_g + (size_t)l*DIM, ln_b + (size_t)l*DIM,
        ref_w2 + (size_t)l*DIM*DIM, ref_b2 + (size_t)l*DIM,
        lp_sum);

    lpnorm_kernel<<<NCLS*DIM/256, 256, 0, stream>>>(
        lp_sum, cnt_i, off, lp_all + (size_t)l*NCLS*DIM);
  }

  final_kernel<<<NCLS, 256, 0, stream>>>(lp_all, cw1, cb1, cw2, cb2, out);
}

// Round 2
// 1648.299 us; speedup vs baseline: 1.1677x; 1.1677x over previous
//
#include <hip/hip_runtime.h>

#define NPTS 65536
#define DIM  512
#define HID  256
#define KCL  16
#define NLVL 3
#define NCLS 64
#define NSEG (NCLS*KCL)
#define EPSF 1e-5f

typedef __bf16 bf16_t;
typedef bf16_t bf16x4 __attribute__((ext_vector_type(4)));
typedef bf16_t bf16x8 __attribute__((ext_vector_type(8)));
typedef float  f32x4  __attribute__((ext_vector_type(4)));

#define LDA 40   // padded LDS row stride in bf16 units (32 data + 8 pad -> 2-way banks = free)

// ============================ W split+transpose (once): W1[l][k][j] -> WhiT/WloT[(l*256+j)][k]
__global__ __launch_bounds__(256) void wsplit_kernel(
    const float* __restrict__ w1, bf16_t* __restrict__ hiT, bf16_t* __restrict__ loT)
{
  int gid = blockIdx.x * 256 + threadIdx.x;   // 0..393215
  int n = gid >> 9, k = gid & 511;
  int l = n >> 8, j = n & 255;
  float v = w1[l*DIM*HID + k*HID + j];
  bf16_t h = (bf16_t)v;
  hiT[gid] = h;
  loT[gid] = (bf16_t)(v - (float)h);
}

// ============================ G = feat @ W1_l via bf16 MFMA, hi/lo compensated ============
// 128x128 tile, 4 waves (each 64x64 as 4x4 of 16x16x32), BK=32. A split fp32->hi/lo in regs.
__global__ __launch_bounds__(256, 2) void gemm_hilo_kernel(
    const float* __restrict__ feat,          // [65536][512] fp32
    const bf16_t* __restrict__ BhiT,         // [256][512] bf16 (level slice, N-major)
    const bf16_t* __restrict__ BloT,
    float* __restrict__ G)                   // [65536][256] fp32
{
  __shared__ __align__(16) bf16_t Ahi[128*LDA];
  __shared__ __align__(16) bf16_t Alo[128*LDA];
  __shared__ __align__(16) bf16_t Bhi[128*LDA];
  __shared__ __align__(16) bf16_t Blo[128*LDA];

  const int t = threadIdx.x;
  const int row0 = blockIdx.x * 128, col0 = blockIdx.y * 128;
  const int w = t >> 6, lane = t & 63;
  const int wm = w & 1, wn = w >> 1;
  const int fm = lane & 15, fq = lane >> 4;   // frag row/col index, k-quad

  f32x4 acc[4][4];
  #pragma unroll
  for (int i = 0; i < 4; i++)
    #pragma unroll
    for (int j = 0; j < 4; j++)
      #pragma unroll
      for (int r = 0; r < 4; r++) acc[i][j][r] = 0.f;

  for (int kc = 0; kc < DIM; kc += 32) {
    __syncthreads();
    // stage A: 128 rows x 32 fp32 -> hi/lo bf16
    #pragma unroll
    for (int p = 0; p < 4; p++) {
      int idx = t + 256*p;                 // 0..1023
      int r = idx >> 3, c = idx & 7;       // row, 16B-chunk (4 fp32)
      float4 v = *(const float4*)&feat[(size_t)(row0 + r)*DIM + kc + c*4];
      bf16x4 hi, lo;
      hi[0] = (bf16_t)v.x; lo[0] = (bf16_t)(v.x - (float)hi[0]);
      hi[1] = (bf16_t)v.y; lo[1] = (bf16_t)(v.y - (float)hi[1]);
      hi[2] = (bf16_t)v.z; lo[2] = (bf16_t)(v.z - (float)hi[2]);
      hi[3] = (bf16_t)v.w; lo[3] = (bf16_t)(v.w - (float)hi[3]);
      *(bf16x4*)&Ahi[r*LDA + c*4] = hi;
      *(bf16x4*)&Alo[r*LDA + c*4] = lo;
    }
    // stage B^T: 128 n-rows x 32 k bf16 (pre-split, pre-transposed)
    #pragma unroll
    for (int p = 0; p < 2; p++) {
      int idx = t + 256*p;                 // 0..511
      int n = idx >> 2, c = idx & 3;       // n-row, 16B-chunk (8 bf16)
      *(bf16x8*)&Bhi[n*LDA + c*8] = *(const bf16x8*)&BhiT[(size_t)(col0 + n)*DIM + kc + c*8];
      *(bf16x8*)&Blo[n*LDA + c*8] = *(const bf16x8*)&BloT[(size_t)(col0 + n)*DIM + kc + c*8];
    }
    __syncthreads();

    bf16x8 ah[4], al[4], bh[4], bl[4];
    #pragma unroll
    for (int mt = 0; mt < 4; mt++) {
      int rr = (wm*64 + mt*16 + fm)*LDA + fq*8;
      ah[mt] = *(bf16x8*)&Ahi[rr];
      al[mt] = *(bf16x8*)&Alo[rr];
    }
    #pragma unroll
    for (int nt = 0; nt < 4; nt++) {
      int rr = (wn*64 + nt*16 + fm)*LDA + fq*8;
      bh[nt] = *(bf16x8*)&Bhi[rr];
      bl[nt] = *(bf16x8*)&Blo[rr];
    }
    #pragma unroll
    for (int mt = 0; mt < 4; mt++)
      #pragma unroll
      for (int nt = 0; nt < 4; nt++) {
        acc[mt][nt] = __builtin_amdgcn_mfma_f32_16x16x32_bf16(ah[mt], bh[nt], acc[mt][nt], 0, 0, 0);
        acc[mt][nt] = __builtin_amdgcn_mfma_f32_16x16x32_bf16(ah[mt], bl[nt], acc[mt][nt], 0, 0, 0);
        acc[mt][nt] = __builtin_amdgcn_mfma_f32_16x16x32_bf16(al[mt], bh[nt], acc[mt][nt], 0, 0, 0);
      }
  }

  // epilogue: C/D layout col=lane&15, row=(lane>>4)*4+reg  [m89-verified]
  #pragma unroll
  for (int mt = 0; mt < 4; mt++)
    #pragma unroll
    for (int nt = 0; nt < 4; nt++) {
      int col = col0 + wn*64 + nt*16 + fm;
      int rowb = row0 + wm*64 + mt*16 + fq*4;
      #pragma unroll
      for (int r = 0; r < 4; r++)
        G[(size_t)(rowb + r)*HID + col] = acc[mt][nt][r];
    }
}

// ============================ offW1b[c][j] = off[c]@W1_l[:,j] + b1[j] =====================
__global__ __launch_bounds__(256) void offgemm_kernel(
    const float* __restrict__ off, const float* __restrict__ w1l,
    const float* __restrict__ b1l, float* __restrict__ offW1b)
{
  int c = blockIdx.x, j = threadIdx.x;
  float a = 0.f;
  #pragma unroll 4
  for (int d = 0; d < DIM; d++)
    a = fmaf(off[c*DIM + d], w1l[d*HID + j], a);
  offW1b[c*HID + j] = a + b1l[j];
}

// ============================ assign2: h=relu(G+offW1b[lab]); logits=hW2+b2; argmax =======
__global__ __launch_bounds__(256) void assign2_kernel(
    const float* __restrict__ G, const float* __restrict__ offW1b,
    const int* __restrict__ labels,
    const float* __restrict__ w2, const float* __restrict__ pb2,
    int* __restrict__ asg, int* __restrict__ cnt)
{
  __shared__ float W2s[256*17];
  __shared__ int   labs[64];
  const int tid = threadIdx.x;
  const int tx = tid & 15, ty = tid >> 4;
  const int row0 = blockIdx.x * 64;

  if (tid < 64) labs[tid] = labels[row0 + tid];
  for (int idx = tid; idx < HID*KCL; idx += 256)
    W2s[(idx >> 4)*17 + (idx & 15)] = w2[idx];
  __syncthreads();

  // load h: thread owns rows ty*4..+3, cols j = q*64 + tx*4 + m
  float h[4][16];
  #pragma unroll
  for (int i = 0; i < 4; i++) {
    int r = ty*4 + i, row = row0 + r, lab = labs[r];
    #pragma unroll
    for (int q = 0; q < 4; q++) {
      float4 g = *(const float4*)&G[(size_t)row*HID + q*64 + tx*4];
      float4 o = *(const float4*)&offW1b[(size_t)lab*HID + q*64 + tx*4];
      h[i][q*4+0] = fmaxf(g.x + o.x, 0.f);
      h[i][q*4+1] = fmaxf(g.y + o.y, 0.f);
      h[i][q*4+2] = fmaxf(g.z + o.z, 0.f);
      h[i][q*4+3] = fmaxf(g.w + o.w, 0.f);
    }
  }

  float part[4][16];
  #pragma unroll
  for (int i = 0; i < 4; i++)
    #pragma unroll
    for (int k2 = 0; k2 < 16; k2++) part[i][k2] = 0.f;

  #pragma unroll
  for (int qi = 0; qi < 16; qi++) {
    int j = (qi >> 2)*64 + tx*4 + (qi & 3);
    float w2r[16];
    #pragma unroll
    for (int s = 0; s < 16; s++) w2r[s] = W2s[j*17 + s];
    #pragma unroll
    for (int i = 0; i < 4; i++)
      #pragma unroll
      for (int k2 = 0; k2 < 16; k2++)
        part[i][k2] = fmaf(h[i][qi], w2r[k2], part[i][k2]);
  }

  #pragma unroll
  for (int ofs = 8; ofs > 0; ofs >>= 1)
    #pragma unroll
    for (int i = 0; i < 4; i++)
      #pragma unroll
      for (int k2 = 0; k2 < 16; k2++)
        part[i][k2] += __shfl_xor(part[i][k2], ofs, 16);

  if (tx == 0) {
    #pragma unroll
    for (int i = 0; i < 4; i++) {
      int r = ty*4 + i;
      float best = part[i][0] + pb2[0];
      int bi = 0;
      #pragma unroll
      for (int k2 = 1; k2 < 16; k2++) {
        float v = part[i][k2] + pb2[k2];
        if (v > best) { best = v; bi = k2; }   // strict > keeps first max
      }
      asg[row0 + r] = bi;
      atomicAdd(&cnt[labs[r]*KCL + bi], 1);
    }
  }
}

// ============================ exclusive scan of segment counts ============================
__global__ void scan_kernel(const int* __restrict__ cnt, int* __restrict__ seg_st,
                            int* __restrict__ cursor)
{
  __shared__ int sc[NSEG];
  int t = threadIdx.x;
  sc[t] = cnt[t];
  __syncthreads();
  for (int ofs = 1; ofs < NSEG; ofs <<= 1) {
    int v = (t >= ofs) ? sc[t - ofs] : 0;
    __syncthreads();
    sc[t] += v;
    __syncthreads();
  }
  seg_st[t + 1] = sc[t];
  if (t == 0) seg_st[0] = 0;
  cursor[t] = sc[t] - cnt[t];
}

// ============================ scatter rows into per-segment lists =========================
__global__ __launch_bounds__(256) void scatter_kernel(
    const int* __restrict__ labels, const int* __restrict__ asg,
    int* __restrict__ cursor, int* __restrict__ rowlist)
{
  int i = blockIdx.x * 256 + threadIdx.x;
  int seg = labels[i]*KCL + asg[i];
  int pos = atomicAdd(&cursor[seg], 1);
  rowlist[pos] = i;
}

// ============================ per-segment feature sums (col-split, no atomics) ============
__global__ __launch_bounds__(256) void means2_kernel(
    const float* __restrict__ feat, const int* __restrict__ rowlist,
    const int* __restrict__ seg_st, float* __restrict__ sums)
{
  int seg = blockIdx.x, q = blockIdx.y;
  int tx = threadIdx.x & 127, ty = threadIdx.x >> 7;
  int s = seg_st[seg], e = seg_st[seg + 1];
  int col = q*128 + tx;
  float a = 0.f;
  int i = s + ty;
  for (; i + 2 < e; i += 4) {
    int r0 = rowlist[i], r1 = rowlist[i + 2];
    a += feat[(size_t)r0*DIM + col];
    a += feat[(size_t)r1*DIM + col];
  }
  for (; i < e; i += 2) a += feat[(size_t)rowlist[i]*DIM + col];
  __shared__ float sh[128];
  if (ty == 1) sh[tx] = a;
  __syncthreads();
  if (ty == 0) sums[(size_t)seg*DIM + col] = a + sh[tx];
}

// ============================ refiner: normalize+off fused; Linear->LN->ReLU->Linear ======
__global__ __launch_bounds__(256, 2) void refine_kernel(
    const float* __restrict__ sums, const int* __restrict__ cnt,
    const float* __restrict__ off,
    const float* __restrict__ w1, const float* __restrict__ pb1,
    const float* __restrict__ g, const float* __restrict__ bgb,
    const float* __restrict__ w2, const float* __restrict__ pb2,
    float* __restrict__ lp_sum)
{
  __shared__ float Ah[8*512];
  __shared__ float Wc[16*512];
  __shared__ float red[2][8][4];
  __shared__ float mS[8], rS[8];
  __shared__ float cw[8], civ[8];

  int t = threadIdx.x;
  int seg0 = blockIdx.x * 8;
  int c = seg0 >> 4;

  if (t < 8) {
    int n = cnt[seg0 + t];
    cw[t] = (float)n;
    civ[t] = 1.f / fmaxf((float)n, 1.f);
  }
  __syncthreads();

  #pragma unroll
  for (int p = 0; p < 16; p++) {
    int idx = t + 256*p;
    int r = idx >> 9, d = idx & 511;
    Ah[idx] = (sums[(size_t)(seg0 + r)*DIM + d] + cw[r]*off[c*DIM + d]) * civ[r];
  }

  float acc[8][2];
  #pragma unroll
  for (int r = 0; r < 8; r++) { acc[r][0] = 0.f; acc[r][1] = 0.f; }

  for (int kc = 0; kc < DIM; kc += 16) {
    __syncthreads();
    #pragma unroll
    for (int p = 0; p < 8; p++) {
      int idx4 = t + 256*p;
      int kr = idx4 >> 7;
      int jv = (idx4 & 127) << 2;
      *(float4*)&Wc[kr*512 + jv] = *(const float4*)&w1[(size_t)(kc + kr)*DIM + jv];
    }
    __syncthreads();
    #pragma unroll
    for (int k = 0; k < 16; k++) {
      float w0 = Wc[k*512 + t];
      float w1v = Wc[k*512 + t + 256];
      #pragma unroll
      for (int r = 0; r < 8; r++) {
        float a = Ah[r*512 + kc + k];
        acc[r][0] = fmaf(a, w0, acc[r][0]);
        acc[r][1] = fmaf(a, w1v, acc[r][1]);
      }
    }
  }
  __syncthreads();

  float v0r[8], v1r[8];
  float tb0 = pb1[t], tb1 = pb1[t + 256];
  #pragma unroll
  for (int r = 0; r < 8; r++) {
    v0r[r] = acc[r][0] + tb0;
    v1r[r] = acc[r][1] + tb1;
    Ah[r*512 + t] = v0r[r];
    Ah[r*512 + t + 256] = v1r[r];
  }
  float s1v[8], s2v[8];
  #pragma unroll
  for (int r = 0; r < 8; r++) {
    s1v[r] = v0r[r] + v1r[r];
    s2v[r] = v0r[r]*v0r[r] + v1r[r]*v1r[r];
  }
  int lane = t & 63, wv = t >> 6;
  #pragma unroll
  for (int ofs = 32; ofs > 0; ofs >>= 1)
    #pragma unroll
    for (int r = 0; r < 8; r++) {
      s1v[r] += __shfl_down(s1v[r], ofs);
      s2v[r] += __shfl_down(s2v[r], ofs);
    }
  if (lane == 0)
    #pragma unroll
    for (int r = 0; r < 8; r++) { red[0][r][wv] = s1v[r]; red[1][r][wv] = s2v[r]; }
  __syncthreads();
  if (t < 8) {
    float a = 0.f, b = 0.f;
    #pragma unroll
    for (int w = 0; w < 4; w++) { a += red[0][t][w]; b += red[1][t][w]; }
    float m = a * (1.f/512.f);
    float var = b * (1.f/512.f) - m*m;
    mS[t] = m;
    rS[t] = rsqrtf(var + EPSF);
  }
  __syncthreads();

  float g0 = g[t], g1 = g[t + 256], bb0 = bgb[t], bb1 = bgb[t + 256];
  #pragma unroll
  for (int r = 0; r < 8; r++) {
    float m = mS[r], rs = rS[r];
    float x0 = fmaxf((Ah[r*512 + t] - m) * rs * g0 + bb0, 0.f);
    float x1 = fmaxf((Ah[r*512 + t + 256] - m) * rs * g1 + bb1, 0.f);
    Ah[r*512 + t] = x0;
    Ah[r*512 + t + 256] = x1;
  }
  __syncthreads();

  float acc2[8][2];
  #pragma unroll
  for (int r = 0; r < 8; r++) { acc2[r][0] = 0.f; acc2[r][1] = 0.f; }
  for (int kc = 0; kc < DIM; kc += 16) {
    __syncthreads();
    #pragma unroll
    for (int p = 0; p < 8; p++) {
      int idx4 = t + 256*p;
      int kr = idx4 >> 7;
      int jv = (idx4 & 127) << 2;
      *(float4*)&Wc[kr*512 + jv] = *(const float4*)&w2[(size_t)(kc + kr)*DIM + jv];
    }
    __syncthreads();
    #pragma unroll
    for (int k = 0; k < 16; k++) {
      float w0 = Wc[k*512 + t];
      float w1v = Wc[k*512 + t + 256];
      #pragma unroll
      for (int r = 0; r < 8; r++) {
        float a = Ah[r*512 + kc + k];
        acc2[r][0] = fmaf(a, w0, acc2[r][0]);
        acc2[r][1] = fmaf(a, w1v, acc2[r][1]);
      }
    }
  }
  float ob0 = pb2[t], ob1 = pb2[t + 256];
  #pragma unroll
  for (int r = 0; r < 8; r++) {
    if (cnt[seg0 + r] > 0) {
      atomicAdd(&lp_sum[c*DIM + t],       acc2[r][0] + ob0);
      atomicAdd(&lp_sum[c*DIM + t + 256], acc2[r][1] + ob1);
    }
  }
}

// ============================ normalize lp, accumulate off ================================
__global__ __launch_bounds__(256) void lpnorm_kernel(
    const float* __restrict__ lp_sum, const int* __restrict__ cnt,
    float* __restrict__ off, float* __restrict__ lp_out)
{
  int gi = blockIdx.x * 256 + threadIdx.x;
  int c = gi >> 9;
  int nes = 0;
  #pragma unroll
  for (int k = 0; k < KCL; k++) nes += (cnt[c*KCL + k] > 0);
  float lp = lp_sum[gi] / (float)nes;
  lp_out[gi] = lp;
  off[gi] += lp;
}

// ============================ final combiner ==============================================
__global__ __launch_bounds__(256) void final_kernel(
    const float* __restrict__ lp_all,
    const float* __restrict__ cw1, const float* __restrict__ cb1,
    const float* __restrict__ cw2, const float* __restrict__ cb2,
    float* __restrict__ out)
{
  __shared__ float comb[NLVL*DIM];
  __shared__ float Wc[16*512];
  __shared__ float Hs[512];
  int t = threadIdx.x;
  int c = blockIdx.x;

  #pragma unroll
  for (int p = 0; p < 6; p++) {
    int idx = t + 256*p;
    comb[idx] = lp_all[(size_t)(idx >> 9)*NCLS*DIM + (size_t)c*DIM + (idx & 511)];
  }

  float a0 = 0.f, a1 = 0.f;
  for (int kc = 0; kc < NLVL*DIM; kc += 16) {
    __syncthreads();
    #pragma unroll
    for (int p = 0; p < 8; p++) {
      int idx4 = t + 256*p;
      int kr = idx4 >> 7;
      int jv = (idx4 & 127) << 2;
      *(float4*)&Wc[kr*512 + jv] = *(const float4*)&cw1[(size_t)(kc + kr)*DIM + jv];
    }
    __syncthreads();
    #pragma unroll
    for (int k = 0; k < 16; k++) {
      float a = comb[kc + k];
      a0 = fmaf(a, Wc[k*512 + t], a0);
      a1 = fmaf(a, Wc[k*512 + t + 256], a1);
    }
  }
  Hs[t] = fmaxf(a0 + cb1[t], 0.f);
  Hs[t + 256] = fmaxf(a1 + cb1[t + 256], 0.f);

  a0 = 0.f; a1 = 0.f;
  for (int kc = 0; kc < DIM; kc += 16) {
    __syncthreads();
    #pragma unroll
    for (int p = 0; p < 8; p++) {
      int idx4 = t + 256*p;
      int kr = idx4 >> 7;
      int jv = (idx4 & 127) << 2;
      *(float4*)&Wc[kr*512 + jv] = *(const float4*)&cw2[(size_t)(kc + kr)*DIM + jv];
    }
    __syncthreads();
    #pragma unroll
    for (int k = 0; k < 16; k++) {
      float h = Hs[kc + k];
      a0 = fmaf(h, Wc[k*512 + t], a0);
      a1 = fmaf(h, Wc[k*512 + t + 256], a1);
    }
  }
  out[(size_t)c*DIM + t] = a0 + cb2[t];
  out[(size_t)c*DIM + t + 256] = a1 + cb2[t + 256];
}

// ============================ launch ======================================================
extern "C" void kernel_launch(void* const* d_in, const int* in_sizes, int n_in,
                              void* d_out, int out_size, void* d_ws, size_t ws_size,
                              hipStream_t stream) {
  const float* feat   = (const float*)d_in[0];
  const int*   labels = (const int*)d_in[1];
  const float* ch_w1  = (const float*)d_in[2];
  const float* ch_b1  = (const float*)d_in[3];
  const float* ch_w2  = (const float*)d_in[4];
  const float* ch_b2  = (const float*)d_in[5];
  const float* ref_w1 = (const float*)d_in[6];
  const float* ref_b1 = (const float*)d_in[7];
  const float* ln_g   = (const float*)d_in[8];
  const float* ln_b   = (const float*)d_in[9];
  const float* ref_w2 = (const float*)d_in[10];
  const float* ref_b2 = (const float*)d_in[11];
  const float* cw1    = (const float*)d_in[12];
  const float* cb1    = (const float*)d_in[13];
  const float* cw2    = (const float*)d_in[14];
  const float* cb2    = (const float*)d_in[15];
  float* out = (float*)d_out;

  float* wsf     = (float*)d_ws;
  float*  off     = wsf;                         // 32768
  float*  lp_sum  = wsf + 32768;                 // 32768
  float*  lp_all  = wsf + 65536;                 // 98304
  float*  sums    = wsf + 163840;                // 524288
  float*  offW1b  = wsf + 688128;                // 16384
  float*  G       = wsf + 704512;                // 16777216
  bf16_t* whiT    = (bf16_t*)(wsf + 17481728);   // 393216 bf16
  bf16_t* wloT    = (bf16_t*)(wsf + 17678336);   // 393216 bf16
  int*    asg     = (int*)(wsf + 17874944);      // 65536
  int*    rowlist = asg + NPTS;                  // 65536
  int*    cnt_i   = rowlist + NPTS;              // 1024
  int*    seg_st  = cnt_i + NSEG;                // 1025
  int*    cursor  = seg_st + NSEG + 8;           // 1024

  hipMemsetAsync(off, 0, NCLS*DIM*sizeof(float), stream);

  wsplit_kernel<<<NLVL*HID*DIM/256, 256, 0, stream>>>(ch_w1, whiT, wloT);

  for (int l = 0; l < NLVL; l++) {
    hipMemsetAsync(cnt_i, 0, NSEG*sizeof(int), stream);
    hipMemsetAsync(lp_sum, 0, NCLS*DIM*sizeof(float), stream);

    gemm_hilo_kernel<<<dim3(NPTS/128, HID/128), 256, 0, stream>>>(
        feat, whiT + (size_t)l*HID*DIM, wloT + (size_t)l*HID*DIM, G);

    offgemm_kernel<<<NCLS, 256, 0, stream>>>(
        off, ch_w1 + (size_t)l*DIM*HID, ch_b1 + (size_t)l*HID, offW1b);

    assign2_kernel<<<NPTS/64, 256, 0, stream>>>(
        G, offW1b, labels,
        ch_w2 + (size_t)l*HID*KCL, ch_b2 + (size_t)l*KCL,
        asg, cnt_i);

    scan_kernel<<<1, NSEG, 0, stream>>>(cnt_i, seg_st, cursor);

    scatter_kernel<<<NPTS/256, 256, 0, stream>>>(labels, asg, cursor, rowlist);

    means2_kernel<<<dim3(NSEG, 4), 256, 0, stream>>>(feat, rowlist, seg_st, sums);

    refine_kernel<<<NSEG/8, 256, 0, stream>>>(
        sums, cnt_i, off,
        ref_w1 + (size_t)l*DIM*DIM, ref_b1 + (size_t)l*DIM,
        ln_g + (size_t)l*DIM, ln_b + (size_t)l*DIM,
        ref_w2 + (size_t)l*DIM*DIM, ref_b2 + (size_t)l*DIM,
        lp_sum);

    lpnorm_kernel<<<NCLS*DIM/256, 256, 0, stream>>>(
        lp_sum, cnt_i, off, lp_all + (size_t)l*NCLS*DIM);
  }

  final_kernel<<<NCLS, 256, 0, stream>>>(lp_all, cw1, cb1, cw2, cb2, out);
}

// Round 3
// 1189.855 us; speedup vs baseline: 1.6176x; 1.3853x over previous
//
#include <hip/hip_runtime.h>

#define NPTS 65536
#define DIM  512
#define HID  256
#define KCL  16
#define NLVL 3
#define NCLS 64
#define NSEG (NCLS*KCL)
#define EPSF 1e-5f

typedef __bf16 bf16_t;
typedef bf16_t bf16x4 __attribute__((ext_vector_type(4)));
typedef bf16_t bf16x8 __attribute__((ext_vector_type(8)));
typedef float  f32x4  __attribute__((ext_vector_type(4)));

#define LDA 40   // padded LDS row stride in bf16 units (2-way banks = free)

// ============================ W split+transpose (once): W1[l][k][j] -> WhiT/WloT[(l*256+j)][k]
__global__ __launch_bounds__(256) void wsplit_kernel(
    const float* __restrict__ w1, bf16_t* __restrict__ hiT, bf16_t* __restrict__ loT)
{
  int gid = blockIdx.x * 256 + threadIdx.x;   // 0..393215
  int n = gid >> 9, k = gid & 511;
  int l = n >> 8, j = n & 255;
  float v = w1[l*DIM*HID + k*HID + j];
  bf16_t h = (bf16_t)v;
  hiT[gid] = h;
  loT[gid] = (bf16_t)(v - (float)h);
}

// ============================ G = feat @ W1_l via bf16 MFMA, hi/lo compensated ============
__global__ __launch_bounds__(256, 2) void gemm_hilo_kernel(
    const float* __restrict__ feat,          // [65536][512] fp32
    const bf16_t* __restrict__ BhiT,         // [256][512] bf16 (level slice, N-major)
    const bf16_t* __restrict__ BloT,
    float* __restrict__ G)                   // [65536][256] fp32
{
  __shared__ __align__(16) bf16_t Ahi[128*LDA];
  __shared__ __align__(16) bf16_t Alo[128*LDA];
  __shared__ __align__(16) bf16_t Bhi[128*LDA];
  __shared__ __align__(16) bf16_t Blo[128*LDA];

  const int t = threadIdx.x;
  const int row0 = blockIdx.x * 128, col0 = blockIdx.y * 128;
  const int w = t >> 6, lane = t & 63;
  const int wm = w & 1, wn = w >> 1;
  const int fm = lane & 15, fq = lane >> 4;

  f32x4 acc[4][4];
  #pragma unroll
  for (int i = 0; i < 4; i++)
    #pragma unroll
    for (int j = 0; j < 4; j++)
      #pragma unroll
      for (int r = 0; r < 4; r++) acc[i][j][r] = 0.f;

  for (int kc = 0; kc < DIM; kc += 32) {
    __syncthreads();
    #pragma unroll
    for (int p = 0; p < 4; p++) {
      int idx = t + 256*p;
      int r = idx >> 3, c = idx & 7;
      float4 v = *(const float4*)&feat[(size_t)(row0 + r)*DIM + kc + c*4];
      bf16x4 hi, lo;
      hi[0] = (bf16_t)v.x; lo[0] = (bf16_t)(v.x - (float)hi[0]);
      hi[1] = (bf16_t)v.y; lo[1] = (bf16_t)(v.y - (float)hi[1]);
      hi[2] = (bf16_t)v.z; lo[2] = (bf16_t)(v.z - (float)hi[2]);
      hi[3] = (bf16_t)v.w; lo[3] = (bf16_t)(v.w - (float)hi[3]);
      *(bf16x4*)&Ahi[r*LDA + c*4] = hi;
      *(bf16x4*)&Alo[r*LDA + c*4] = lo;
    }
    #pragma unroll
    for (int p = 0; p < 2; p++) {
      int idx = t + 256*p;
      int n = idx >> 2, c = idx & 3;
      *(bf16x8*)&Bhi[n*LDA + c*8] = *(const bf16x8*)&BhiT[(size_t)(col0 + n)*DIM + kc + c*8];
      *(bf16x8*)&Blo[n*LDA + c*8] = *(const bf16x8*)&BloT[(size_t)(col0 + n)*DIM + kc + c*8];
    }
    __syncthreads();

    bf16x8 ah[4], al[4], bh[4], bl[4];
    #pragma unroll
    for (int mt = 0; mt < 4; mt++) {
      int rr = (wm*64 + mt*16 + fm)*LDA + fq*8;
      ah[mt] = *(bf16x8*)&Ahi[rr];
      al[mt] = *(bf16x8*)&Alo[rr];
    }
    #pragma unroll
    for (int nt = 0; nt < 4; nt++) {
      int rr = (wn*64 + nt*16 + fm)*LDA + fq*8;
      bh[nt] = *(bf16x8*)&Bhi[rr];
      bl[nt] = *(bf16x8*)&Blo[rr];
    }
    #pragma unroll
    for (int mt = 0; mt < 4; mt++)
      #pragma unroll
      for (int nt = 0; nt < 4; nt++) {
        acc[mt][nt] = __builtin_amdgcn_mfma_f32_16x16x32_bf16(ah[mt], bh[nt], acc[mt][nt], 0, 0, 0);
        acc[mt][nt] = __builtin_amdgcn_mfma_f32_16x16x32_bf16(ah[mt], bl[nt], acc[mt][nt], 0, 0, 0);
        acc[mt][nt] = __builtin_amdgcn_mfma_f32_16x16x32_bf16(al[mt], bh[nt], acc[mt][nt], 0, 0, 0);
      }
  }

  #pragma unroll
  for (int mt = 0; mt < 4; mt++)
    #pragma unroll
    for (int nt = 0; nt < 4; nt++) {
      int col = col0 + wn*64 + nt*16 + fm;
      int rowb = row0 + wm*64 + mt*16 + fq*4;
      #pragma unroll
      for (int r = 0; r < 4; r++)
        G[(size_t)(rowb + r)*HID + col] = acc[mt][nt][r];
    }
}

// ============================ offW1b[c][j] = off[c]@W1_l[:,j] + b1[j] =====================
__global__ __launch_bounds__(256) void offgemm_kernel(
    const float* __restrict__ off, const float* __restrict__ w1l,
    const float* __restrict__ b1l, float* __restrict__ offW1b)
{
  int c = blockIdx.x, j = threadIdx.x;
  float a = 0.f;
  #pragma unroll 4
  for (int d = 0; d < DIM; d++)
    a = fmaf(off[c*DIM + d], w1l[d*HID + j], a);
  offW1b[c*HID + j] = a + b1l[j];
}

// ============================ assign2: h=relu(G+offW1b[lab]); logits=hW2+b2; argmax =======
__global__ __launch_bounds__(256) void assign2_kernel(
    const float* __restrict__ G, const float* __restrict__ offW1b,
    const int* __restrict__ labels,
    const float* __restrict__ w2, const float* __restrict__ pb2,
    int* __restrict__ asg, int* __restrict__ cnt)
{
  __shared__ float W2s[256*17];
  __shared__ int   labs[64];
  const int tid = threadIdx.x;
  const int tx = tid & 15, ty = tid >> 4;
  const int row0 = blockIdx.x * 64;

  if (tid < 64) labs[tid] = labels[row0 + tid];
  for (int idx = tid; idx < HID*KCL; idx += 256)
    W2s[(idx >> 4)*17 + (idx & 15)] = w2[idx];
  __syncthreads();

  float h[4][16];
  #pragma unroll
  for (int i = 0; i < 4; i++) {
    int r = ty*4 + i, row = row0 + r, lab = labs[r];
    #pragma unroll
    for (int q = 0; q < 4; q++) {
      float4 g = *(const float4*)&G[(size_t)row*HID + q*64 + tx*4];
      float4 o = *(const float4*)&offW1b[(size_t)lab*HID + q*64 + tx*4];
      h[i][q*4+0] = fmaxf(g.x + o.x, 0.f);
      h[i][q*4+1] = fmaxf(g.y + o.y, 0.f);
      h[i][q*4+2] = fmaxf(g.z + o.z, 0.f);
      h[i][q*4+3] = fmaxf(g.w + o.w, 0.f);
    }
  }

  float part[4][16];
  #pragma unroll
  for (int i = 0; i < 4; i++)
    #pragma unroll
    for (int k2 = 0; k2 < 16; k2++) part[i][k2] = 0.f;

  #pragma unroll
  for (int qi = 0; qi < 16; qi++) {
    int j = (qi >> 2)*64 + tx*4 + (qi & 3);
    float w2r[16];
    #pragma unroll
    for (int s = 0; s < 16; s++) w2r[s] = W2s[j*17 + s];
    #pragma unroll
    for (int i = 0; i < 4; i++)
      #pragma unroll
      for (int k2 = 0; k2 < 16; k2++)
        part[i][k2] = fmaf(h[i][qi], w2r[k2], part[i][k2]);
  }

  #pragma unroll
  for (int ofs = 8; ofs > 0; ofs >>= 1)
    #pragma unroll
    for (int i = 0; i < 4; i++)
      #pragma unroll
      for (int k2 = 0; k2 < 16; k2++)
        part[i][k2] += __shfl_xor(part[i][k2], ofs, 16);

  if (tx == 0) {
    #pragma unroll
    for (int i = 0; i < 4; i++) {
      int r = ty*4 + i;
      float best = part[i][0] + pb2[0];
      int bi = 0;
      #pragma unroll
      for (int k2 = 1; k2 < 16; k2++) {
        float v = part[i][k2] + pb2[k2];
        if (v > best) { best = v; bi = k2; }
      }
      asg[row0 + r] = bi;
      atomicAdd(&cnt[labs[r]*KCL + bi], 1);
    }
  }
}

// ============================ exclusive scan of segment counts ============================
__global__ void scan_kernel(const int* __restrict__ cnt, int* __restrict__ seg_st,
                            int* __restrict__ cursor)
{
  __shared__ int sc[NSEG];
  int t = threadIdx.x;
  sc[t] = cnt[t];
  __syncthreads();
  for (int ofs = 1; ofs < NSEG; ofs <<= 1) {
    int v = (t >= ofs) ? sc[t - ofs] : 0;
    __syncthreads();
    sc[t] += v;
    __syncthreads();
  }
  seg_st[t + 1] = sc[t];
  if (t == 0) seg_st[0] = 0;
  cursor[t] = sc[t] - cnt[t];
}

// ============================ scatter rows into per-segment sorted lists ==================
__global__ __launch_bounds__(256) void scatter_kernel(
    const int* __restrict__ labels, const int* __restrict__ asg,
    int* __restrict__ cursor, int* __restrict__ rowlist, int* __restrict__ seglist)
{
  int i = blockIdx.x * 256 + threadIdx.x;
  int seg = labels[i]*KCL + asg[i];
  int pos = atomicAdd(&cursor[seg], 1);
  rowlist[pos] = i;
  seglist[pos] = seg;
}

// ============================ balanced segmented sums over sorted rowlist =================
// grid (NPTS/64, DIM/256); block 256. Chunk = 64 sorted rows; thread owns one col.
__global__ __launch_bounds__(256) void means3_kernel(
    const float* __restrict__ feat, const int* __restrict__ rowlist,
    const int* __restrict__ seglist, float* __restrict__ sums)
{
  __shared__ int rows[64];
  __shared__ int segs[65];
  int t = threadIdx.x;
  int i0 = blockIdx.x * 64;
  int col = blockIdx.y * 256 + t;
  if (t < 64) { rows[t] = rowlist[i0 + t]; segs[t] = seglist[i0 + t]; }
  if (t == 64) segs[64] = -1;   // always flush at chunk end
  __syncthreads();
  float acc = 0.f;
  for (int base = 0; base < 64; base += 16) {
    float v[16];
    #pragma unroll
    for (int j = 0; j < 16; j++)
      v[j] = feat[(size_t)rows[base + j]*DIM + col];    // 16 independent loads in flight
    #pragma unroll
    for (int j = 0; j < 16; j++) {
      acc += v[j];
      if (segs[base + j] != segs[base + j + 1]) {       // block-uniform branch
        atomicAdd(&sums[(size_t)segs[base + j]*DIM + col], acc);
        acc = 0.f;
      }
    }
  }
}

// ============================ refiner: normalize+off fused; Linear->LN->ReLU->Linear ======
__global__ __launch_bounds__(256, 2) void refine_kernel(
    const float* __restrict__ sums, const int* __restrict__ cnt,
    const float* __restrict__ off,
    const float* __restrict__ w1, const float* __restrict__ pb1,
    const float* __restrict__ g, const float* __restrict__ bgb,
    const float* __restrict__ w2, const float* __restrict__ pb2,
    float* __restrict__ lp_sum)
{
  __shared__ float Ah[8*512];
  __shared__ float Wc[16*512];
  __shared__ float red[2][8][4];
  __shared__ float mS[8], rS[8];
  __shared__ float cw[8], civ[8];

  int t = threadIdx.x;
  int seg0 = blockIdx.x * 8;
  int c = seg0 >> 4;

  if (t < 8) {
    int n = cnt[seg0 + t];
    cw[t] = (float)n;
    civ[t] = 1.f / fmaxf((float)n, 1.f);
  }
  __syncthreads();

  #pragma unroll
  for (int p = 0; p < 16; p++) {
    int idx = t + 256*p;
    int r = idx >> 9, d = idx & 511;
    Ah[idx] = (sums[(size_t)(seg0 + r)*DIM + d] + cw[r]*off[c*DIM + d]) * civ[r];
  }

  float acc[8][2];
  #pragma unroll
  for (int r = 0; r < 8; r++) { acc[r][0] = 0.f; acc[r][1] = 0.f; }

  for (int kc = 0; kc < DIM; kc += 16) {
    __syncthreads();
    #pragma unroll
    for (int p = 0; p < 8; p++) {
      int idx4 = t + 256*p;
      int kr = idx4 >> 7;
      int jv = (idx4 & 127) << 2;
      *(float4*)&Wc[kr*512 + jv] = *(const float4*)&w1[(size_t)(kc + kr)*DIM + jv];
    }
    __syncthreads();
    #pragma unroll
    for (int k = 0; k < 16; k++) {
      float w0 = Wc[k*512 + t];
      float w1v = Wc[k*512 + t + 256];
      #pragma unroll
      for (int r = 0; r < 8; r++) {
        float a = Ah[r*512 + kc + k];
        acc[r][0] = fmaf(a, w0, acc[r][0]);
        acc[r][1] = fmaf(a, w1v, acc[r][1]);
      }
    }
  }
  __syncthreads();

  float v0r[8], v1r[8];
  float tb0 = pb1[t], tb1 = pb1[t + 256];
  #pragma unroll
  for (int r = 0; r < 8; r++) {
    v0r[r] = acc[r][0] + tb0;
    v1r[r] = acc[r][1] + tb1;
    Ah[r*512 + t] = v0r[r];
    Ah[r*512 + t + 256] = v1r[r];
  }
  float s1v[8], s2v[8];
  #pragma unroll
  for (int r = 0; r < 8; r++) {
    s1v[r] = v0r[r] + v1r[r];
    s2v[r] = v0r[r]*v0r[r] + v1r[r]*v1r[r];
  }
  int lane = t & 63, wv = t >> 6;
  #pragma unroll
  for (int ofs = 32; ofs > 0; ofs >>= 1)
    #pragma unroll
    for (int r = 0; r < 8; r++) {
      s1v[r] += __shfl_down(s1v[r], ofs);
      s2v[r] += __shfl_down(s2v[r], ofs);
    }
  if (lane == 0)
    #pragma unroll
    for (int r = 0; r < 8; r++) { red[0][r][wv] = s1v[r]; red[1][r][wv] = s2v[r]; }
  __syncthreads();
  if (t < 8) {
    float a = 0.f, b = 0.f;
    #pragma unroll
    for (int w = 0; w < 4; w++) { a += red[0][t][w]; b += red[1][t][w]; }
    float m = a * (1.f/512.f);
    float var = b * (1.f/512.f) - m*m;
    mS[t] = m;
    rS[t] = rsqrtf(var + EPSF);
  }
  __syncthreads();

  float g0 = g[t], g1 = g[t + 256], bb0 = bgb[t], bb1 = bgb[t + 256];
  #pragma unroll
  for (int r = 0; r < 8; r++) {
    float m = mS[r], rs = rS[r];
    float x0 = fmaxf((Ah[r*512 + t] - m) * rs * g0 + bb0, 0.f);
    float x1 = fmaxf((Ah[r*512 + t + 256] - m) * rs * g1 + bb1, 0.f);
    Ah[r*512 + t] = x0;
    Ah[r*512 + t + 256] = x1;
  }
  __syncthreads();

  float acc2[8][2];
  #pragma unroll
  for (int r = 0; r < 8; r++) { acc2[r][0] = 0.f; acc2[r][1] = 0.f; }
  for (int kc = 0; kc < DIM; kc += 16) {
    __syncthreads();
    #pragma unroll
    for (int p = 0; p < 8; p++) {
      int idx4 = t + 256*p;
      int kr = idx4 >> 7;
      int jv = (idx4 & 127) << 2;
      *(float4*)&Wc[kr*512 + jv] = *(const float4*)&w2[(size_t)(kc + kr)*DIM + jv];
    }
    __syncthreads();
    #pragma unroll
    for (int k = 0; k < 16; k++) {
      float w0 = Wc[k*512 + t];
      float w1v = Wc[k*512 + t + 256];
      #pragma unroll
      for (int r = 0; r < 8; r++) {
        float a = Ah[r*512 + kc + k];
        acc2[r][0] = fmaf(a, w0, acc2[r][0]);
        acc2[r][1] = fmaf(a, w1v, acc2[r][1]);
      }
    }
  }
  float ob0 = pb2[t], ob1 = pb2[t + 256];
  #pragma unroll
  for (int r = 0; r < 8; r++) {
    if (cnt[seg0 + r] > 0) {
      atomicAdd(&lp_sum[c*DIM + t],       acc2[r][0] + ob0);
      atomicAdd(&lp_sum[c*DIM + t + 256], acc2[r][1] + ob1);
    }
  }
}

// ============================ normalize lp, accumulate off ================================
__global__ __launch_bounds__(256) void lpnorm_kernel(
    const float* __restrict__ lp_sum, const int* __restrict__ cnt,
    float* __restrict__ off, float* __restrict__ lp_out)
{
  int gi = blockIdx.x * 256 + threadIdx.x;
  int c = gi >> 9;
  int nes = 0;
  #pragma unroll
  for (int k = 0; k < KCL; k++) nes += (cnt[c*KCL + k] > 0);
  float lp = lp_sum[gi] / (float)nes;
  lp_out[gi] = lp;
  off[gi] += lp;
}

// ============================ final combiner ==============================================
__global__ __launch_bounds__(256) void final_kernel(
    const float* __restrict__ lp_all,
    const float* __restrict__ cw1, const float* __restrict__ cb1,
    const float* __restrict__ cw2, const float* __restrict__ cb2,
    float* __restrict__ out)
{
  __shared__ float comb[NLVL*DIM];
  __shared__ float Wc[16*512];
  __shared__ float Hs[512];
  int t = threadIdx.x;
  int c = blockIdx.x;

  #pragma unroll
  for (int p = 0; p < 6; p++) {
    int idx = t + 256*p;
    comb[idx] = lp_all[(size_t)(idx >> 9)*NCLS*DIM + (size_t)c*DIM + (idx & 511)];
  }

  float a0 = 0.f, a1 = 0.f;
  for (int kc = 0; kc < NLVL*DIM; kc += 16) {
    __syncthreads();
    #pragma unroll
    for (int p = 0; p < 8; p++) {
      int idx4 = t + 256*p;
      int kr = idx4 >> 7;
      int jv = (idx4 & 127) << 2;
      *(float4*)&Wc[kr*512 + jv] = *(const float4*)&cw1[(size_t)(kc + kr)*DIM + jv];
    }
    __syncthreads();
    #pragma unroll
    for (int k = 0; k < 16; k++) {
      float a = comb[kc + k];
      a0 = fmaf(a, Wc[k*512 + t], a0);
      a1 = fmaf(a, Wc[k*512 + t + 256], a1);
    }
  }
  Hs[t] = fmaxf(a0 + cb1[t], 0.f);
  Hs[t + 256] = fmaxf(a1 + cb1[t + 256], 0.f);

  a0 = 0.f; a1 = 0.f;
  for (int kc = 0; kc < DIM; kc += 16) {
    __syncthreads();
    #pragma unroll
    for (int p = 0; p < 8; p++) {
      int idx4 = t + 256*p;
      int kr = idx4 >> 7;
      int jv = (idx4 & 127) << 2;
      *(float4*)&Wc[kr*512 + jv] = *(const float4*)&cw2[(size_t)(kc + kr)*DIM + jv];
    }
    __syncthreads();
    #pragma unroll
    for (int k = 0; k < 16; k++) {
      float h = Hs[kc + k];
      a0 = fmaf(h, Wc[k*512 + t], a0);
      a1 = fmaf(h, Wc[k*512 + t + 256], a1);
    }
  }
  out[(size_t)c*DIM + t] = a0 + cb2[t];
  out[(size_t)c*DIM + t + 256] = a1 + cb2[t + 256];
}

// ============================ launch ======================================================
extern "C" void kernel_launch(void* const* d_in, const int* in_sizes, int n_in,
                              void* d_out, int out_size, void* d_ws, size_t ws_size,
                              hipStream_t stream) {
  const float* feat   = (const float*)d_in[0];
  const int*   labels = (const int*)d_in[1];
  const float* ch_w1  = (const float*)d_in[2];
  const float* ch_b1  = (const float*)d_in[3];
  const float* ch_w2  = (const float*)d_in[4];
  const float* ch_b2  = (const float*)d_in[5];
  const float* ref_w1 = (const float*)d_in[6];
  const float* ref_b1 = (const float*)d_in[7];
  const float* ln_g   = (const float*)d_in[8];
  const float* ln_b   = (const float*)d_in[9];
  const float* ref_w2 = (const float*)d_in[10];
  const float* ref_b2 = (const float*)d_in[11];
  const float* cw1    = (const float*)d_in[12];
  const float* cb1    = (const float*)d_in[13];
  const float* cw2    = (const float*)d_in[14];
  const float* cb2    = (const float*)d_in[15];
  float* out = (float*)d_out;

  float* wsf     = (float*)d_ws;
  float*  off     = wsf;                         // 32768
  float*  lp_sum  = wsf + 32768;                 // 32768
  float*  lp_all  = wsf + 65536;                 // 98304
  float*  sums    = wsf + 163840;                // 524288
  float*  offW1b  = wsf + 688128;                // 16384
  float*  G       = wsf + 704512;                // 16777216
  bf16_t* whiT    = (bf16_t*)(wsf + 17481728);   // 393216 bf16
  bf16_t* wloT    = (bf16_t*)(wsf + 17678336);   // 393216 bf16
  int*    asg     = (int*)(wsf + 17874944);      // 65536
  int*    rowlist = asg + NPTS;                  // 65536
  int*    seglist = rowlist + NPTS;              // 65536
  int*    cnt_i   = seglist + NPTS;              // 1024
  int*    seg_st  = cnt_i + NSEG;                // 1025
  int*    cursor  = seg_st + NSEG + 8;           // 1024

  hipMemsetAsync(off, 0, NCLS*DIM*sizeof(float), stream);

  wsplit_kernel<<<NLVL*HID*DIM/256, 256, 0, stream>>>(ch_w1, whiT, wloT);

  for (int l = 0; l < NLVL; l++) {
    hipMemsetAsync(cnt_i, 0, NSEG*sizeof(int), stream);
    hipMemsetAsync(lp_sum, 0, NCLS*DIM*sizeof(float), stream);
    hipMemsetAsync(sums, 0, NSEG*DIM*sizeof(float), stream);

    gemm_hilo_kernel<<<dim3(NPTS/128, HID/128), 256, 0, stream>>>(
        feat, whiT + (size_t)l*HID*DIM, wloT + (size_t)l*HID*DIM, G);

    offgemm_kernel<<<NCLS, 256, 0, stream>>>(
        off, ch_w1 + (size_t)l*DIM*HID, ch_b1 + (size_t)l*HID, offW1b);

    assign2_kernel<<<NPTS/64, 256, 0, stream>>>(
        G, offW1b, labels,
        ch_w2 + (size_t)l*HID*KCL, ch_b2 + (size_t)l*KCL,
        asg, cnt_i);

    scan_kernel<<<1, NSEG, 0, stream>>>(cnt_i, seg_st, cursor);

    scatter_kernel<<<NPTS/256, 256, 0, stream>>>(labels, asg, cursor, rowlist, seglist);

    means3_kernel<<<dim3(NPTS/64, DIM/256), 256, 0, stream>>>(
        feat, rowlist, seglist, sums);

    refine_kernel<<<NSEG/8, 256, 0, stream>>>(
        sums, cnt_i, off,
        ref_w1 + (size_t)l*DIM*DIM, ref_b1 + (size_t)l*DIM,
        ln_g + (size_t)l*DIM, ln_b + (size_t)l*DIM,
        ref_w2 + (size_t)l*DIM*DIM, ref_b2 + (size_t)l*DIM,
        lp_sum);

    lpnorm_kernel<<<NCLS*DIM/256, 256, 0, stream>>>(
        lp_sum, cnt_i, off, lp_all + (size_t)l*NCLS*DIM);
  }

  final_kernel<<<NCLS, 256, 0, stream>>>(lp_all, cw1, cb1, cw2, cb2, out);
}

// Round 4
// 1115.249 us; speedup vs baseline: 1.7258x; 1.0669x over previous
//
#include <hip/hip_runtime.h>

#define NPTS 65536
#define DIM  512
#define HID  256
#define KCL  16
#define NLVL 3
#define NCLS 64
#define NSEG (NCLS*KCL)
#define EPSF 1e-5f

typedef __bf16 bf16_t;
typedef bf16_t bf16x4 __attribute__((ext_vector_type(4)));
typedef bf16_t bf16x8 __attribute__((ext_vector_type(8)));
typedef float  f32x4  __attribute__((ext_vector_type(4)));

#define LDA 40   // padded LDS row stride in bf16 units (2-way banks = free)

// ============================ W split+transpose (once): W1[l][k][j] -> WhiT/WloT[(l*256+j)][k]
__global__ __launch_bounds__(256) void wsplit_kernel(
    const float* __restrict__ w1, bf16_t* __restrict__ hiT, bf16_t* __restrict__ loT)
{
  int gid = blockIdx.x * 256 + threadIdx.x;   // 0..393215
  int n = gid >> 9, k = gid & 511;
  int l = n >> 8, j = n & 255;
  float v = w1[l*DIM*HID + k*HID + j];
  bf16_t h = (bf16_t)v;
  hiT[gid] = h;
  loT[gid] = (bf16_t)(v - (float)h);
}

// ============================ G = feat @ W1 via bf16 MFMA, hi/lo compensated ==============
// 128x128 tile; ldg = G row stride (768 hoisted / 256 per-level).
__global__ __launch_bounds__(256, 2) void gemm_hilo_kernel(
    const float* __restrict__ feat,          // [65536][512] fp32
    const bf16_t* __restrict__ BhiT,         // [ncols][512] bf16 (N-major)
    const bf16_t* __restrict__ BloT,
    float* __restrict__ G, int ldg)
{
  __shared__ __align__(16) bf16_t Ahi[128*LDA];
  __shared__ __align__(16) bf16_t Alo[128*LDA];
  __shared__ __align__(16) bf16_t Bhi[128*LDA];
  __shared__ __align__(16) bf16_t Blo[128*LDA];

  const int t = threadIdx.x;
  const int row0 = blockIdx.x * 128, col0 = blockIdx.y * 128;
  const int w = t >> 6, lane = t & 63;
  const int wm = w & 1, wn = w >> 1;
  const int fm = lane & 15, fq = lane >> 4;

  f32x4 acc[4][4];
  #pragma unroll
  for (int i = 0; i < 4; i++)
    #pragma unroll
    for (int j = 0; j < 4; j++)
      #pragma unroll
      for (int r = 0; r < 4; r++) acc[i][j][r] = 0.f;

  for (int kc = 0; kc < DIM; kc += 32) {
    __syncthreads();
    #pragma unroll
    for (int p = 0; p < 4; p++) {
      int idx = t + 256*p;
      int r = idx >> 3, c = idx & 7;
      float4 v = *(const float4*)&feat[(size_t)(row0 + r)*DIM + kc + c*4];
      bf16x4 hi, lo;
      hi[0] = (bf16_t)v.x; lo[0] = (bf16_t)(v.x - (float)hi[0]);
      hi[1] = (bf16_t)v.y; lo[1] = (bf16_t)(v.y - (float)hi[1]);
      hi[2] = (bf16_t)v.z; lo[2] = (bf16_t)(v.z - (float)hi[2]);
      hi[3] = (bf16_t)v.w; lo[3] = (bf16_t)(v.w - (float)hi[3]);
      *(bf16x4*)&Ahi[r*LDA + c*4] = hi;
      *(bf16x4*)&Alo[r*LDA + c*4] = lo;
    }
    #pragma unroll
    for (int p = 0; p < 2; p++) {
      int idx = t + 256*p;
      int n = idx >> 2, c = idx & 3;
      *(bf16x8*)&Bhi[n*LDA + c*8] = *(const bf16x8*)&BhiT[(size_t)(col0 + n)*DIM + kc + c*8];
      *(bf16x8*)&Blo[n*LDA + c*8] = *(const bf16x8*)&BloT[(size_t)(col0 + n)*DIM + kc + c*8];
    }
    __syncthreads();

    bf16x8 ah[4], al[4], bh[4], bl[4];
    #pragma unroll
    for (int mt = 0; mt < 4; mt++) {
      int rr = (wm*64 + mt*16 + fm)*LDA + fq*8;
      ah[mt] = *(bf16x8*)&Ahi[rr];
      al[mt] = *(bf16x8*)&Alo[rr];
    }
    #pragma unroll
    for (int nt = 0; nt < 4; nt++) {
      int rr = (wn*64 + nt*16 + fm)*LDA + fq*8;
      bh[nt] = *(bf16x8*)&Bhi[rr];
      bl[nt] = *(bf16x8*)&Blo[rr];
    }
    #pragma unroll
    for (int mt = 0; mt < 4; mt++)
      #pragma unroll
      for (int nt = 0; nt < 4; nt++) {
        acc[mt][nt] = __builtin_amdgcn_mfma_f32_16x16x32_bf16(ah[mt], bh[nt], acc[mt][nt], 0, 0, 0);
        acc[mt][nt] = __builtin_amdgcn_mfma_f32_16x16x32_bf16(ah[mt], bl[nt], acc[mt][nt], 0, 0, 0);
        acc[mt][nt] = __builtin_amdgcn_mfma_f32_16x16x32_bf16(al[mt], bh[nt], acc[mt][nt], 0, 0, 0);
      }
  }

  #pragma unroll
  for (int mt = 0; mt < 4; mt++)
    #pragma unroll
    for (int nt = 0; nt < 4; nt++) {
      int col = col0 + wn*64 + nt*16 + fm;
      int rowb = row0 + wm*64 + mt*16 + fq*4;
      #pragma unroll
      for (int r = 0; r < 4; r++)
        G[(size_t)(rowb + r)*ldg + col] = acc[mt][nt][r];
    }
}

// ============================ offW1b[c][j] = off[c]@W1_l[:,j] + b1[j] =====================
__global__ __launch_bounds__(256) void offgemm_kernel(
    const float* __restrict__ off, const float* __restrict__ w1l,
    const float* __restrict__ b1l, float* __restrict__ offW1b)
{
  int c = blockIdx.x, j = threadIdx.x;
  float a = 0.f;
  #pragma unroll 4
  for (int d = 0; d < DIM; d++)
    a = fmaf(off[c*DIM + d], w1l[d*HID + j], a);
  offW1b[c*HID + j] = a + b1l[j];
}

// ============================ assign2: h=relu(Gl+offW1b[lab]); logits=hW2+b2; argmax ======
__global__ __launch_bounds__(256) void assign2_kernel(
    const float* __restrict__ Gl, int ldg, const float* __restrict__ offW1b,
    const int* __restrict__ labels,
    const float* __restrict__ w2, const float* __restrict__ pb2,
    int* __restrict__ asg, int* __restrict__ cnt)
{
  __shared__ float W2s[256*17];
  __shared__ int   labs[64];
  const int tid = threadIdx.x;
  const int tx = tid & 15, ty = tid >> 4;
  const int row0 = blockIdx.x * 64;

  if (tid < 64) labs[tid] = labels[row0 + tid];
  for (int idx = tid; idx < HID*KCL; idx += 256)
    W2s[(idx >> 4)*17 + (idx & 15)] = w2[idx];
  __syncthreads();

  float h[4][16];
  #pragma unroll
  for (int i = 0; i < 4; i++) {
    int r = ty*4 + i, row = row0 + r, lab = labs[r];
    #pragma unroll
    for (int q = 0; q < 4; q++) {
      float4 g = *(const float4*)&Gl[(size_t)row*ldg + q*64 + tx*4];
      float4 o = *(const float4*)&offW1b[(size_t)lab*HID + q*64 + tx*4];
      h[i][q*4+0] = fmaxf(g.x + o.x, 0.f);
      h[i][q*4+1] = fmaxf(g.y + o.y, 0.f);
      h[i][q*4+2] = fmaxf(g.z + o.z, 0.f);
      h[i][q*4+3] = fmaxf(g.w + o.w, 0.f);
    }
  }

  float part[4][16];
  #pragma unroll
  for (int i = 0; i < 4; i++)
    #pragma unroll
    for (int k2 = 0; k2 < 16; k2++) part[i][k2] = 0.f;

  #pragma unroll
  for (int qi = 0; qi < 16; qi++) {
    int j = (qi >> 2)*64 + tx*4 + (qi & 3);
    float w2r[16];
    #pragma unroll
    for (int s = 0; s < 16; s++) w2r[s] = W2s[j*17 + s];
    #pragma unroll
    for (int i = 0; i < 4; i++)
      #pragma unroll
      for (int k2 = 0; k2 < 16; k2++)
        part[i][k2] = fmaf(h[i][qi], w2r[k2], part[i][k2]);
  }

  #pragma unroll
  for (int ofs = 8; ofs > 0; ofs >>= 1)
    #pragma unroll
    for (int i = 0; i < 4; i++)
      #pragma unroll
      for (int k2 = 0; k2 < 16; k2++)
        part[i][k2] += __shfl_xor(part[i][k2], ofs, 16);

  if (tx == 0) {
    #pragma unroll
    for (int i = 0; i < 4; i++) {
      int r = ty*4 + i;
      float best = part[i][0] + pb2[0];
      int bi = 0;
      #pragma unroll
      for (int k2 = 1; k2 < 16; k2++) {
        float v = part[i][k2] + pb2[k2];
        if (v > best) { best = v; bi = k2; }
      }
      asg[row0 + r] = bi;
      atomicAdd(&cnt[labs[r]*KCL + bi], 1);
    }
  }
}

// ============================ exclusive scan of segment counts ============================
__global__ void scan_kernel(const int* __restrict__ cnt, int* __restrict__ seg_st,
                            int* __restrict__ cursor)
{
  __shared__ int sc[NSEG];
  int t = threadIdx.x;
  sc[t] = cnt[t];
  __syncthreads();
  for (int ofs = 1; ofs < NSEG; ofs <<= 1) {
    int v = (t >= ofs) ? sc[t - ofs] : 0;
    __syncthreads();
    sc[t] += v;
    __syncthreads();
  }
  seg_st[t + 1] = sc[t];
  if (t == 0) seg_st[0] = 0;
  cursor[t] = sc[t] - cnt[t];
}

// ============================ scatter rows into per-segment sorted lists ==================
__global__ __launch_bounds__(256) void scatter_kernel(
    const int* __restrict__ labels, const int* __restrict__ asg,
    int* __restrict__ cursor, int* __restrict__ rowlist, int* __restrict__ seglist)
{
  int i = blockIdx.x * 256 + threadIdx.x;
  int seg = labels[i]*KCL + asg[i];
  int pos = atomicAdd(&cursor[seg], 1);
  rowlist[pos] = i;
  seglist[pos] = seg;
}

// ============================ balanced segmented sums over sorted rowlist =================
__global__ __launch_bounds__(256) void means3_kernel(
    const float* __restrict__ feat, const int* __restrict__ rowlist,
    const int* __restrict__ seglist, float* __restrict__ sums)
{
  __shared__ int rows[64];
  __shared__ int segs[65];
  int t = threadIdx.x;
  int i0 = blockIdx.x * 64;
  int col = blockIdx.y * 256 + t;
  if (t < 64) { rows[t] = rowlist[i0 + t]; segs[t] = seglist[i0 + t]; }
  if (t == 64) segs[64] = -1;
  __syncthreads();
  float acc = 0.f;
  for (int base = 0; base < 64; base += 16) {
    float v[16];
    #pragma unroll
    for (int j = 0; j < 16; j++)
      v[j] = feat[(size_t)rows[base + j]*DIM + col];
    #pragma unroll
    for (int j = 0; j < 16; j++) {
      acc += v[j];
      if (segs[base + j] != segs[base + j + 1]) {
        atomicAdd(&sums[(size_t)segs[base + j]*DIM + col], acc);
        acc = 0.f;
      }
    }
  }
}

// ============================ refiner: normalize+off fused; Linear->LN->ReLU->Linear ======
__global__ __launch_bounds__(256, 2) void refine_kernel(
    const float* __restrict__ sums, const int* __restrict__ cnt,
    const float* __restrict__ off,
    const float* __restrict__ w1, const float* __restrict__ pb1,
    const float* __restrict__ g, const float* __restrict__ bgb,
    const float* __restrict__ w2, const float* __restrict__ pb2,
    float* __restrict__ lp_sum)
{
  __shared__ float Ah[8*512];
  __shared__ float Wc[16*512];
  __shared__ float red[2][8][4];
  __shared__ float mS[8], rS[8];
  __shared__ float cw[8], civ[8];

  int t = threadIdx.x;
  int seg0 = blockIdx.x * 8;
  int c = seg0 >> 4;

  if (t < 8) {
    int n = cnt[seg0 + t];
    cw[t] = (float)n;
    civ[t] = 1.f / fmaxf((float)n, 1.f);
  }
  __syncthreads();

  #pragma unroll
  for (int p = 0; p < 16; p++) {
    int idx = t + 256*p;
    int r = idx >> 9, d = idx & 511;
    Ah[idx] = (sums[(size_t)(seg0 + r)*DIM + d] + cw[r]*off[c*DIM + d]) * civ[r];
  }

  float acc[8][2];
  #pragma unroll
  for (int r = 0; r < 8; r++) { acc[r][0] = 0.f; acc[r][1] = 0.f; }

  for (int kc = 0; kc < DIM; kc += 16) {
    __syncthreads();
    #pragma unroll
    for (int p = 0; p < 8; p++) {
      int idx4 = t + 256*p;
      int kr = idx4 >> 7;
      int jv = (idx4 & 127) << 2;
      *(float4*)&Wc[kr*512 + jv] = *(const float4*)&w1[(size_t)(kc + kr)*DIM + jv];
    }
    __syncthreads();
    #pragma unroll
    for (int k = 0; k < 16; k++) {
      float w0 = Wc[k*512 + t];
      float w1v = Wc[k*512 + t + 256];
      #pragma unroll
      for (int r = 0; r < 8; r++) {
        float a = Ah[r*512 + kc + k];
        acc[r][0] = fmaf(a, w0, acc[r][0]);
        acc[r][1] = fmaf(a, w1v, acc[r][1]);
      }
    }
  }
  __syncthreads();

  float v0r[8], v1r[8];
  float tb0 = pb1[t], tb1 = pb1[t + 256];
  #pragma unroll
  for (int r = 0; r < 8; r++) {
    v0r[r] = acc[r][0] + tb0;
    v1r[r] = acc[r][1] + tb1;
    Ah[r*512 + t] = v0r[r];
    Ah[r*512 + t + 256] = v1r[r];
  }
  float s1v[8], s2v[8];
  #pragma unroll
  for (int r = 0; r < 8; r++) {
    s1v[r] = v0r[r] + v1r[r];
    s2v[r] = v0r[r]*v0r[r] + v1r[r]*v1r[r];
  }
  int lane = t & 63, wv = t >> 6;
  #pragma unroll
  for (int ofs = 32; ofs > 0; ofs >>= 1)
    #pragma unroll
    for (int r = 0; r < 8; r++) {
      s1v[r] += __shfl_down(s1v[r], ofs);
      s2v[r] += __shfl_down(s2v[r], ofs);
    }
  if (lane == 0)
    #pragma unroll
    for (int r = 0; r < 8; r++) { red[0][r][wv] = s1v[r]; red[1][r][wv] = s2v[r]; }
  __syncthreads();
  if (t < 8) {
    float a = 0.f, b = 0.f;
    #pragma unroll
    for (int w = 0; w < 4; w++) { a += red[0][t][w]; b += red[1][t][w]; }
    float m = a * (1.f/512.f);
    float var = b * (1.f/512.f) - m*m;
    mS[t] = m;
    rS[t] = rsqrtf(var + EPSF);
  }
  __syncthreads();

  float g0 = g[t], g1 = g[t + 256], bb0 = bgb[t], bb1 = bgb[t + 256];
  #pragma unroll
  for (int r = 0; r < 8; r++) {
    float m = mS[r], rs = rS[r];
    float x0 = fmaxf((Ah[r*512 + t] - m) * rs * g0 + bb0, 0.f);
    float x1 = fmaxf((Ah[r*512 + t + 256] - m) * rs * g1 + bb1, 0.f);
    Ah[r*512 + t] = x0;
    Ah[r*512 + t + 256] = x1;
  }
  __syncthreads();

  float acc2[8][2];
  #pragma unroll
  for (int r = 0; r < 8; r++) { acc2[r][0] = 0.f; acc2[r][1] = 0.f; }
  for (int kc = 0; kc < DIM; kc += 16) {
    __syncthreads();
    #pragma unroll
    for (int p = 0; p < 8; p++) {
      int idx4 = t + 256*p;
      int kr = idx4 >> 7;
      int jv = (idx4 & 127) << 2;
      *(float4*)&Wc[kr*512 + jv] = *(const float4*)&w2[(size_t)(kc + kr)*DIM + jv];
    }
    __syncthreads();
    #pragma unroll
    for (int k = 0; k < 16; k++) {
      float w0 = Wc[k*512 + t];
      float w1v = Wc[k*512 + t + 256];
      #pragma unroll
      for (int r = 0; r < 8; r++) {
        float a = Ah[r*512 + kc + k];
        acc2[r][0] = fmaf(a, w0, acc2[r][0]);
        acc2[r][1] = fmaf(a, w1v, acc2[r][1]);
      }
    }
  }
  float ob0 = pb2[t], ob1 = pb2[t + 256];
  #pragma unroll
  for (int r = 0; r < 8; r++) {
    if (cnt[seg0 + r] > 0) {
      atomicAdd(&lp_sum[c*DIM + t],       acc2[r][0] + ob0);
      atomicAdd(&lp_sum[c*DIM + t + 256], acc2[r][1] + ob1);
    }
  }
}

// ============================ normalize lp, accumulate off ================================
__global__ __launch_bounds__(256) void lpnorm_kernel(
    const float* __restrict__ lp_sum, const int* __restrict__ cnt,
    float* __restrict__ off, float* __restrict__ lp_out)
{
  int gi = blockIdx.x * 256 + threadIdx.x;
  int c = gi >> 9;
  int nes = 0;
  #pragma unroll
  for (int k = 0; k < KCL; k++) nes += (cnt[c*KCL + k] > 0);
  float lp = lp_sum[gi] / (float)nes;
  lp_out[gi] = lp;
  off[gi] += lp;
}

// ============================ final stage 1: Hacc += comb[64x1536] @ cw1 (K-split) ========
// grid (8 n-chunks, 12 k-chunks), 256 thr. comb[c][l*512+d] = lp_all[(l*64+c)*512+d].
__global__ __launch_bounds__(256) void fgemm1_kernel(
    const float* __restrict__ lp_all, const float* __restrict__ cw1,
    float* __restrict__ Hacc)
{
  __shared__ float As[64*132];   // [m][k], pad 132
  __shared__ float Ws[128*64];   // [k][n]
  int t = threadIdx.x;
  int nc = blockIdx.x * 64, kc = blockIdx.y * 128;

  #pragma unroll
  for (int p = 0; p < 8; p++) {
    int i = t + 256*p;                 // float4 idx 0..2047
    int m = i >> 5, k0 = (i & 31) << 2;
    int k = kc + k0;
    int l = k >> 9, d = k & 511;
    *(float4*)&As[m*132 + k0] = *(const float4*)&lp_all[(size_t)(l*NCLS + m)*DIM + d];
  }
  #pragma unroll
  for (int p = 0; p < 8; p++) {
    int i = t + 256*p;
    int k = i >> 4, n0 = (i & 15) << 2;
    *(float4*)&Ws[k*64 + n0] = *(const float4*)&cw1[(size_t)(kc + k)*DIM + nc + n0];
  }
  __syncthreads();

  int tn = (t & 15) * 4, tmg = (t >> 4) * 4;
  float acc[4][4];
  #pragma unroll
  for (int i = 0; i < 4; i++)
    #pragma unroll
    for (int j = 0; j < 4; j++) acc[i][j] = 0.f;

  for (int k = 0; k < 128; k += 4) {
    float4 a[4], w[4];
    #pragma unroll
    for (int i = 0; i < 4; i++) a[i] = *(float4*)&As[(tmg + i)*132 + k];
    #pragma unroll
    for (int j = 0; j < 4; j++) w[j] = *(float4*)&Ws[(k + j)*64 + tn];
    #pragma unroll
    for (int kk = 0; kk < 4; kk++) {
      float wv[4] = {w[kk].x, w[kk].y, w[kk].z, w[kk].w};
      float av[4] = {a[0][kk], a[1][kk], a[2][kk], a[3][kk]};
      #pragma unroll
      for (int i = 0; i < 4; i++)
        #pragma unroll
        for (int j = 0; j < 4; j++)
          acc[i][j] = fmaf(av[i], wv[j], acc[i][j]);
    }
  }
  #pragma unroll
  for (int i = 0; i < 4; i++)
    #pragma unroll
    for (int j = 0; j < 4; j++)
      atomicAdd(&Hacc[(size_t)(tmg + i)*DIM + nc + tn + j], acc[i][j]);
}

// ============================ final stage 2: Oacc += relu(Hacc+cb1) @ cw2 (K-split) =======
__global__ __launch_bounds__(256) void fgemm2_kernel(
    const float* __restrict__ Hacc, const float* __restrict__ cb1,
    const float* __restrict__ cw2, float* __restrict__ Oacc)
{
  __shared__ float As[64*132];
  __shared__ float Ws[128*64];
  int t = threadIdx.x;
  int nc = blockIdx.x * 64, kc = blockIdx.y * 128;

  #pragma unroll
  for (int p = 0; p < 8; p++) {
    int i = t + 256*p;
    int m = i >> 5, k0 = (i & 31) << 2;
    float4 v = *(const float4*)&Hacc[(size_t)m*DIM + kc + k0];
    float4 b = *(const float4*)&cb1[kc + k0];
    v.x = fmaxf(v.x + b.x, 0.f); v.y = fmaxf(v.y + b.y, 0.f);
    v.z = fmaxf(v.z + b.z, 0.f); v.w = fmaxf(v.w + b.w, 0.f);
    *(float4*)&As[m*132 + k0] = v;
  }
  #pragma unroll
  for (int p = 0; p < 8; p++) {
    int i = t + 256*p;
    int k = i >> 4, n0 = (i & 15) << 2;
    *(float4*)&Ws[k*64 + n0] = *(const float4*)&cw2[(size_t)(kc + k)*DIM + nc + n0];
  }
  __syncthreads();

  int tn = (t & 15) * 4, tmg = (t >> 4) * 4;
  float acc[4][4];
  #pragma unroll
  for (int i = 0; i < 4; i++)
    #pragma unroll
    for (int j = 0; j < 4; j++) acc[i][j] = 0.f;

  for (int k = 0; k < 128; k += 4) {
    float4 a[4], w[4];
    #pragma unroll
    for (int i = 0; i < 4; i++) a[i] = *(float4*)&As[(tmg + i)*132 + k];
    #pragma unroll
    for (int j = 0; j < 4; j++) w[j] = *(float4*)&Ws[(k + j)*64 + tn];
    #pragma unroll
    for (int kk = 0; kk < 4; kk++) {
      float wv[4] = {w[kk].x, w[kk].y, w[kk].z, w[kk].w};
      float av[4] = {a[0][kk], a[1][kk], a[2][kk], a[3][kk]};
      #pragma unroll
      for (int i = 0; i < 4; i++)
        #pragma unroll
        for (int j = 0; j < 4; j++)
          acc[i][j] = fmaf(av[i], wv[j], acc[i][j]);
    }
  }
  #pragma unroll
  for (int i = 0; i < 4; i++)
    #pragma unroll
    for (int j = 0; j < 4; j++)
      atomicAdd(&Oacc[(size_t)(tmg + i)*DIM + nc + tn + j], acc[i][j]);
}

// ============================ final stage 3: out = Oacc + cb2 =============================
__global__ __launch_bounds__(256) void fbias_kernel(
    const float* __restrict__ Oacc, const float* __restrict__ cb2,
    float* __restrict__ out)
{
  int gi = blockIdx.x * 256 + threadIdx.x;
  out[gi] = Oacc[gi] + cb2[gi & 511];
}

// ============================ launch ======================================================
extern "C" void kernel_launch(void* const* d_in, const int* in_sizes, int n_in,
                              void* d_out, int out_size, void* d_ws, size_t ws_size,
                              hipStream_t stream) {
  const float* feat   = (const float*)d_in[0];
  const int*   labels = (const int*)d_in[1];
  const float* ch_w1  = (const float*)d_in[2];
  const float* ch_b1  = (const float*)d_in[3];
  const float* ch_w2  = (const float*)d_in[4];
  const float* ch_b2  = (const float*)d_in[5];
  const float* ref_w1 = (const float*)d_in[6];
  const float* ref_b1 = (const float*)d_in[7];
  const float* ln_g   = (const float*)d_in[8];
  const float* ln_b   = (const float*)d_in[9];
  const float* ref_w2 = (const float*)d_in[10];
  const float* ref_b2 = (const float*)d_in[11];
  const float* cw1    = (const float*)d_in[12];
  const float* cb1    = (const float*)d_in[13];
  const float* cw2    = (const float*)d_in[14];
  const float* cb2    = (const float*)d_in[15];
  float* out = (float*)d_out;

  float* wsf = (float*)d_ws;
  float* off    = wsf;               // 32768
  float* lp_sum = off + 32768;       // 32768
  float* lp_all = lp_sum + 32768;    // 98304
  float* sums   = lp_all + 98304;    // 524288
  float* offW1b = sums + 524288;     // 16384
  float* Hacc   = offW1b + 16384;    // 32768
  float* Oacc   = Hacc + 32768;      // 32768
  float* G      = Oacc + 32768;      // variable

  size_t g_hoist = (size_t)NPTS * (NLVL*HID);       // 50,331,648 floats
  size_t g_level = (size_t)NPTS * HID;              // 16,777,216 floats
  size_t tail_f  = 2*(NLVL*HID*DIM/2)               // whiT+wloT in float units (393216)
                 + (3*NPTS + NSEG + NSEG + 16 + NSEG) / 1 /* ints */;
  size_t base_f  = (size_t)(G - wsf);
  bool hoist = ws_size >= (base_f + g_hoist + tail_f + 1024) * 4;
  size_t g_elems = hoist ? g_hoist : g_level;
  int ldg = hoist ? NLVL*HID : HID;

  bf16_t* whiT = (bf16_t*)(G + g_elems);            // 393216 bf16
  bf16_t* wloT = whiT + (size_t)NLVL*HID*DIM;       // 393216 bf16
  int* asg     = (int*)(wloT + (size_t)NLVL*HID*DIM);
  int* rowlist = asg + NPTS;
  int* seglist = rowlist + NPTS;
  int* cnt_i   = seglist + NPTS;
  int* seg_st  = cnt_i + NSEG;
  int* cursor  = seg_st + NSEG + 16;

  hipMemsetAsync(off, 0, NCLS*DIM*sizeof(float), stream);

  wsplit_kernel<<<NLVL*HID*DIM/256, 256, 0, stream>>>(ch_w1, whiT, wloT);

  if (hoist)
    gemm_hilo_kernel<<<dim3(NPTS/128, NLVL*HID/128), 256, 0, stream>>>(
        feat, whiT, wloT, G, ldg);

  for (int l = 0; l < NLVL; l++) {
    hipMemsetAsync(cnt_i, 0, NSEG*sizeof(int), stream);
    hipMemsetAsync(lp_sum, 0, NCLS*DIM*sizeof(float), stream);
    hipMemsetAsync(sums, 0, NSEG*DIM*sizeof(float), stream);

    if (!hoist)
      gemm_hilo_kernel<<<dim3(NPTS/128, HID/128), 256, 0, stream>>>(
          feat, whiT + (size_t)l*HID*DIM, wloT + (size_t)l*HID*DIM, G, ldg);

    offgemm_kernel<<<NCLS, 256, 0, stream>>>(
        off, ch_w1 + (size_t)l*DIM*HID, ch_b1 + (size_t)l*HID, offW1b);

    assign2_kernel<<<NPTS/64, 256, 0, stream>>>(
        hoist ? (G + (size_t)l*HID) : G, ldg, offW1b, labels,
        ch_w2 + (size_t)l*HID*KCL, ch_b2 + (size_t)l*KCL,
        asg, cnt_i);

    scan_kernel<<<1, NSEG, 0, stream>>>(cnt_i, seg_st, cursor);

    scatter_kernel<<<NPTS/256, 256, 0, stream>>>(labels, asg, cursor, rowlist, seglist);

    means3_kernel<<<dim3(NPTS/64, DIM/256), 256, 0, stream>>>(
        feat, rowlist, seglist, sums);

    refine_kernel<<<NSEG/8, 256, 0, stream>>>(
        sums, cnt_i, off,
        ref_w1 + (size_t)l*DIM*DIM, ref_b1 + (size_t)l*DIM,
        ln_g + (size_t)l*DIM, ln_b + (size_t)l*DIM,
        ref_w2 + (size_t)l*DIM*DIM, ref_b2 + (size_t)l*DIM,
        lp_sum);

    lpnorm_kernel<<<NCLS*DIM/256, 256, 0, stream>>>(
        lp_sum, cnt_i, off, lp_all + (size_t)l*NCLS*DIM);
  }

  // final combiner, K-split parallel
  hipMemsetAsync(Hacc, 0, 2*NCLS*DIM*sizeof(float), stream);   // Hacc+Oacc contiguous
  fgemm1_kernel<<<dim3(DIM/64, NLVL*DIM/128), 256, 0, stream>>>(lp_all, cw1, Hacc);
  fgemm2_kernel<<<dim3(DIM/64, DIM/128), 256, 0, stream>>>(Hacc, cb1, cw2, Oacc);
  fbias_kernel<<<NCLS*DIM/256, 256, 0, stream>>>(Oacc, cb2, out);
}

// Round 5
// 1031.270 us; speedup vs baseline: 1.8664x; 1.0814x over previous
//
#include <hip/hip_runtime.h>

#define NPTS 65536
#define DIM  512
#define HID  256
#define KCL  16
#define NLVL 3
#define NCLS 64
#define NSEG (NCLS*KCL)
#define EPSF 1e-5f

typedef __bf16 bf16_t;
typedef bf16_t bf16x4 __attribute__((ext_vector_type(4)));
typedef bf16_t bf16x8 __attribute__((ext_vector_type(8)));
typedef float  f32x4  __attribute__((ext_vector_type(4)));

// ============================ W1 split+transpose (once): W1[l][k][j] -> [(l*256+j)][k] ====
__global__ __launch_bounds__(256) void wsplit_kernel(
    const float* __restrict__ w1, bf16_t* __restrict__ hiT, bf16_t* __restrict__ loT)
{
  int gid = blockIdx.x * 256 + threadIdx.x;   // 0..393215
  int n = gid >> 9, k = gid & 511;
  int l = n >> 8, j = n & 255;
  float v = w1[l*DIM*HID + k*HID + j];
  bf16_t h = (bf16_t)v;
  hiT[gid] = h;
  loT[gid] = (bf16_t)(v - (float)h);
}

// ============================ ref-W split+transpose: W[l][k][n](512x512) -> [(l*512+n)][k] =
__global__ __launch_bounds__(256) void wsplit2_kernel(
    const float* __restrict__ w, bf16_t* __restrict__ hiT, bf16_t* __restrict__ loT)
{
  int gid = blockIdx.x * 256 + threadIdx.x;   // 0..786431
  int n512 = gid >> 9, k = gid & 511;
  int l = n512 >> 9, n = n512 & 511;
  float v = w[(size_t)l*DIM*DIM + (size_t)k*DIM + n];
  bf16_t h = (bf16_t)v;
  hiT[gid] = h;
  loT[gid] = (bf16_t)(v - (float)h);
}

// ============================ C = A(fp32) @ B via bf16 MFMA, hi/lo compensated ============
// 128x128 tile, K=512. Fragment-major LDS: all ds reads/writes lane-sequential (conflict-free).
__global__ __launch_bounds__(256, 2) void gemm_hilo_kernel(
    const float* __restrict__ A,             // [M][512] fp32
    const bf16_t* __restrict__ BhiT,         // [ncols][512] bf16 (N-major)
    const bf16_t* __restrict__ BloT,
    float* __restrict__ G, int ldg, int ntG)
{
  __shared__ __align__(16) bf16_t Ahi[4096];   // (grp*64 + fq*16 + fm)*8 + j
  __shared__ __align__(16) bf16_t Alo[4096];
  __shared__ __align__(16) bf16_t Bhi[4096];
  __shared__ __align__(16) bf16_t Blo[4096];

  const int t = threadIdx.x;
  const int row0 = blockIdx.x * 128, col0 = blockIdx.y * 128;
  const int w = t >> 6, lane = t & 63;
  const int wm = w & 1, wn = w >> 1;
  const int fm = lane & 15, fq = lane >> 4;

  f32x4 acc[4][4];
  #pragma unroll
  for (int i = 0; i < 4; i++)
    #pragma unroll
    for (int j = 0; j < 4; j++)
      #pragma unroll
      for (int r = 0; r < 4; r++) acc[i][j][r] = 0.f;

  for (int kc = 0; kc < DIM; kc += 32) {
    __syncthreads();
    // stage A: e = t+256p; half=e&1, fmr=(e>>1)&15, fqr=(e>>5)&3, mt=e>>7
    #pragma unroll
    for (int p = 0; p < 4; p++) {
      int e = t + 256*p;
      int row = ((e >> 7) << 4) + ((e >> 1) & 15);
      int kof = ((e >> 5) & 3)*8 + (e & 1)*4;
      float4 v = *(const float4*)&A[(size_t)(row0 + row)*DIM + kc + kof];
      bf16x4 hi, lo;
      hi[0] = (bf16_t)v.x; lo[0] = (bf16_t)(v.x - (float)hi[0]);
      hi[1] = (bf16_t)v.y; lo[1] = (bf16_t)(v.y - (float)hi[1]);
      hi[2] = (bf16_t)v.z; lo[2] = (bf16_t)(v.z - (float)hi[2]);
      hi[3] = (bf16_t)v.w; lo[3] = (bf16_t)(v.w - (float)hi[3]);
      *(bf16x4*)&Ahi[e*4] = hi;            // byte addr e*8: lane-sequential, 2-way = free
      *(bf16x4*)&Alo[e*4] = lo;
    }
    // stage B: e = t+256p; fmr=e&15, fqr=(e>>4)&3, nt=e>>6
    #pragma unroll
    for (int p = 0; p < 2; p++) {
      int e = t + 256*p;
      int n = ((e >> 6) << 4) + (e & 15);
      int kof = ((e >> 4) & 3)*8;
      *(bf16x8*)&Bhi[e*8] = *(const bf16x8*)&BhiT[(size_t)(col0 + n)*DIM + kc + kof];
      *(bf16x8*)&Blo[e*8] = *(const bf16x8*)&BloT[(size_t)(col0 + n)*DIM + kc + kof];
    }
    __syncthreads();

    bf16x8 ah[4], al[4], bh[4], bl[4];
    #pragma unroll
    for (int mt = 0; mt < 4; mt++) {
      int idx = ((wm*4 + mt)*64 + lane)*8;   // base + lane*16B: conflict-free
      ah[mt] = *(bf16x8*)&Ahi[idx];
      al[mt] = *(bf16x8*)&Alo[idx];
    }
    #pragma unroll
    for (int nt = 0; nt < 4; nt++) {
      int idx = ((wn*4 + nt)*64 + lane)*8;
      bh[nt] = *(bf16x8*)&Bhi[idx];
      bl[nt] = *(bf16x8*)&Blo[idx];
    }
    #pragma unroll
    for (int mt = 0; mt < 4; mt++)
      #pragma unroll
      for (int nt = 0; nt < 4; nt++) {
        acc[mt][nt] = __builtin_amdgcn_mfma_f32_16x16x32_bf16(ah[mt], bh[nt], acc[mt][nt], 0, 0, 0);
        acc[mt][nt] = __builtin_amdgcn_mfma_f32_16x16x32_bf16(ah[mt], bl[nt], acc[mt][nt], 0, 0, 0);
        acc[mt][nt] = __builtin_amdgcn_mfma_f32_16x16x32_bf16(al[mt], bh[nt], acc[mt][nt], 0, 0, 0);
      }
  }

  // epilogue: C/D layout col=lane&15, row=(lane>>4)*4+reg
  #pragma unroll
  for (int mt = 0; mt < 4; mt++)
    #pragma unroll
    for (int nt = 0; nt < 4; nt++) {
      int col = col0 + wn*64 + nt*16 + fm;
      int rowb = row0 + wm*64 + mt*16 + fq*4;
      #pragma unroll
      for (int r = 0; r < 4; r++) {
        float* p = &G[(size_t)(rowb + r)*ldg + col];
        if (ntG) __builtin_nontemporal_store(acc[mt][nt][r], p);
        else *p = acc[mt][nt][r];
      }
    }
}

// ============================ offW1b[c][j] = off[c]@W1_l[:,j] + b1[j] =====================
__global__ __launch_bounds__(256) void offgemm_kernel(
    const float* __restrict__ off, const float* __restrict__ w1l,
    const float* __restrict__ b1l, float* __restrict__ offW1b)
{
  int c = blockIdx.x, j = threadIdx.x;
  float a = 0.f;
  #pragma unroll 4
  for (int d = 0; d < DIM; d++)
    a = fmaf(off[c*DIM + d], w1l[d*HID + j], a);
  offW1b[c*HID + j] = a + b1l[j];
}

// ============================ assign2: h=relu(Gl+offW1b[lab]); logits=hW2+b2; argmax ======
__global__ __launch_bounds__(256) void assign2_kernel(
    const float* __restrict__ Gl, int ldg, const float* __restrict__ offW1b,
    const int* __restrict__ labels,
    const float* __restrict__ w2, const float* __restrict__ pb2,
    int* __restrict__ asg, int* __restrict__ cnt)
{
  __shared__ float W2s[256*17];
  __shared__ int   labs[64];
  const int tid = threadIdx.x;
  const int tx = tid & 15, ty = tid >> 4;
  const int row0 = blockIdx.x * 64;

  if (tid < 64) labs[tid] = labels[row0 + tid];
  for (int idx = tid; idx < HID*KCL; idx += 256)
    W2s[(idx >> 4)*17 + (idx & 15)] = w2[idx];
  __syncthreads();

  float h[4][16];
  #pragma unroll
  for (int i = 0; i < 4; i++) {
    int r = ty*4 + i, row = row0 + r, lab = labs[r];
    #pragma unroll
    for (int q = 0; q < 4; q++) {
      float4 g = *(const float4*)&Gl[(size_t)row*ldg + q*64 + tx*4];
      float4 o = *(const float4*)&offW1b[(size_t)lab*HID + q*64 + tx*4];
      h[i][q*4+0] = fmaxf(g.x + o.x, 0.f);
      h[i][q*4+1] = fmaxf(g.y + o.y, 0.f);
      h[i][q*4+2] = fmaxf(g.z + o.z, 0.f);
      h[i][q*4+3] = fmaxf(g.w + o.w, 0.f);
    }
  }

  float part[4][16];
  #pragma unroll
  for (int i = 0; i < 4; i++)
    #pragma unroll
    for (int k2 = 0; k2 < 16; k2++) part[i][k2] = 0.f;

  #pragma unroll
  for (int qi = 0; qi < 16; qi++) {
    int j = (qi >> 2)*64 + tx*4 + (qi & 3);
    float w2r[16];
    #pragma unroll
    for (int s = 0; s < 16; s++) w2r[s] = W2s[j*17 + s];
    #pragma unroll
    for (int i = 0; i < 4; i++)
      #pragma unroll
      for (int k2 = 0; k2 < 16; k2++)
        part[i][k2] = fmaf(h[i][qi], w2r[k2], part[i][k2]);
  }

  #pragma unroll
  for (int ofs = 8; ofs > 0; ofs >>= 1)
    #pragma unroll
    for (int i = 0; i < 4; i++)
      #pragma unroll
      for (int k2 = 0; k2 < 16; k2++)
        part[i][k2] += __shfl_xor(part[i][k2], ofs, 16);

  if (tx == 0) {
    #pragma unroll
    for (int i = 0; i < 4; i++) {
      int r = ty*4 + i;
      float best = part[i][0] + pb2[0];
      int bi = 0;
      #pragma unroll
      for (int k2 = 1; k2 < 16; k2++) {
        float v = part[i][k2] + pb2[k2];
        if (v > best) { best = v; bi = k2; }
      }
      asg[row0 + r] = bi;
      atomicAdd(&cnt[labs[r]*KCL + bi], 1);
    }
  }
}

// ============================ exclusive scan (shuffle-based, 3 barriers) ==================
__global__ void scan_kernel(const int* __restrict__ cnt, int* __restrict__ seg_st,
                            int* __restrict__ cursor)
{
  int t = threadIdx.x;                         // 256 threads, 4 segs each
  int4 v = *(const int4*)&cnt[t*4];
  int a0 = v.x, a1 = v.x + v.y, a2 = a1 + v.z, tot = a2 + v.w;
  int lane = t & 63, w = t >> 6;
  int sc = tot;
  #pragma unroll
  for (int ofs = 1; ofs < 64; ofs <<= 1) {
    int u = __shfl_up(sc, ofs);
    if (lane >= ofs) sc += u;
  }
  __shared__ int wt[4];
  if (lane == 63) wt[w] = sc;
  __syncthreads();
  int base = 0;
  #pragma unroll
  for (int i = 0; i < 4; i++) if (i < w) base += wt[i];
  int excl = base + sc - tot;
  seg_st[t*4 + 1] = excl + a0;
  seg_st[t*4 + 2] = excl + a1;
  seg_st[t*4 + 3] = excl + a2;
  seg_st[t*4 + 4] = excl + tot;
  if (t == 0) seg_st[0] = 0;
  int4 cur = {excl, excl + a0, excl + a1, excl + a2};
  *(int4*)&cursor[t*4] = cur;
}

// ============================ scatter rows into per-segment sorted lists ==================
__global__ __launch_bounds__(256) void scatter_kernel(
    const int* __restrict__ labels, const int* __restrict__ asg,
    int* __restrict__ cursor, int* __restrict__ rowlist, int* __restrict__ seglist)
{
  int i = blockIdx.x * 256 + threadIdx.x;
  int seg = labels[i]*KCL + asg[i];
  int pos = atomicAdd(&cursor[seg], 1);
  rowlist[pos] = i;
  seglist[pos] = seg;
}

// ============================ balanced segmented sums over sorted rowlist =================
__global__ __launch_bounds__(256) void means3_kernel(
    const float* __restrict__ feat, const int* __restrict__ rowlist,
    const int* __restrict__ seglist, float* __restrict__ sums)
{
  __shared__ int rows[64];
  __shared__ int segs[65];
  int t = threadIdx.x;
  int i0 = blockIdx.x * 64;
  int col = blockIdx.y * 256 + t;
  if (t < 64) { rows[t] = rowlist[i0 + t]; segs[t] = seglist[i0 + t]; }
  if (t == 64) segs[64] = -1;
  __syncthreads();
  float acc = 0.f;
  for (int base = 0; base < 64; base += 16) {
    float v[16];
    #pragma unroll
    for (int j = 0; j < 16; j++)
      v[j] = feat[(size_t)rows[base + j]*DIM + col];
    #pragma unroll
    for (int j = 0; j < 16; j++) {
      acc += v[j];
      if (segs[base + j] != segs[base + j + 1]) {
        atomicAdd(&sums[(size_t)segs[base + j]*DIM + col], acc);
        acc = 0.f;
      }
    }
  }
}

// ============================ A[seg] = (sums[seg] + cnt*off[class]) / max(cnt,1) ==========
__global__ __launch_bounds__(256) void meannorm_kernel(
    const float* __restrict__ sums, const int* __restrict__ cnt,
    const float* __restrict__ off, float* __restrict__ A)
{
  int gi = blockIdx.x * 256 + threadIdx.x;   // 0..524287
  int seg = gi >> 9, d = gi & 511, c = seg >> 4;
  float n = (float)cnt[seg];
  A[gi] = (sums[gi] + n*off[c*DIM + d]) / fmaxf(n, 1.f);
}

// ============================ H = relu(LN(Y1 + b1) * g + b) ===============================
__global__ __launch_bounds__(256) void lnrelu_kernel(
    const float* __restrict__ Y1, const float* __restrict__ b1,
    const float* __restrict__ g, const float* __restrict__ b,
    float* __restrict__ H)
{
  int r = blockIdx.x, t = threadIdx.x;
  float x0 = Y1[(size_t)r*DIM + t]       + b1[t];
  float x1 = Y1[(size_t)r*DIM + t + 256] + b1[t + 256];
  float s1 = x0 + x1, s2 = x0*x0 + x1*x1;
  #pragma unroll
  for (int ofs = 32; ofs > 0; ofs >>= 1) {
    s1 += __shfl_xor(s1, ofs);
    s2 += __shfl_xor(s2, ofs);
  }
  __shared__ float r1[4], r2[4];
  int lane = t & 63, w = t >> 6;
  if (lane == 0) { r1[w] = s1; r2[w] = s2; }
  __syncthreads();
  s1 = r1[0] + r1[1] + r1[2] + r1[3];
  s2 = r2[0] + r2[1] + r2[2] + r2[3];
  float m = s1 * (1.f/512.f);
  float var = s2 * (1.f/512.f) - m*m;
  float rs = rsqrtf(var + EPSF);
  H[(size_t)r*DIM + t]       = fmaxf((x0 - m)*rs*g[t]       + b[t],       0.f);
  H[(size_t)r*DIM + t + 256] = fmaxf((x1 - m)*rs*g[t + 256] + b[t + 256], 0.f);
}

// ============================ lp[c] = mean over non-empty k of (Y2[c*16+k]+b2); off += lp ==
__global__ __launch_bounds__(256) void protoreduce_kernel(
    const float* __restrict__ Y2, const float* __restrict__ b2,
    const int* __restrict__ cnt, float* __restrict__ off, float* __restrict__ lp_out)
{
  int c = blockIdx.x >> 1;
  int d = (blockIdx.x & 1)*256 + threadIdx.x;
  float bb = b2[d];
  float s = 0.f; int nes = 0;
  #pragma unroll
  for (int k = 0; k < KCL; k++) {
    if (cnt[c*KCL + k] > 0) { nes++; s += Y2[(size_t)(c*KCL + k)*DIM + d] + bb; }
  }
  float lp = s / (float)nes;
  lp_out[c*DIM + d] = lp;
  off[c*DIM + d] += lp;
}

// ============================ final stage 1: Hacc += comb[64x1536] @ cw1 (K-split) ========
__global__ __launch_bounds__(256) void fgemm1_kernel(
    const float* __restrict__ lp_all, const float* __restrict__ cw1,
    float* __restrict__ Hacc)
{
  __shared__ float As[64*132];
  __shared__ float Ws[128*64];
  int t = threadIdx.x;
  int nc = blockIdx.x * 64, kc = blockIdx.y * 128;

  #pragma unroll
  for (int p = 0; p < 8; p++) {
    int i = t + 256*p;
    int m = i >> 5, k0 = (i & 31) << 2;
    int k = kc + k0;
    int l = k >> 9, d = k & 511;
    *(float4*)&As[m*132 + k0] = *(const float4*)&lp_all[(size_t)(l*NCLS + m)*DIM + d];
  }
  #pragma unroll
  for (int p = 0; p < 8; p++) {
    int i = t + 256*p;
    int k = i >> 4, n0 = (i & 15) << 2;
    *(float4*)&Ws[k*64 + n0] = *(const float4*)&cw1[(size_t)(kc + k)*DIM + nc + n0];
  }
  __syncthreads();

  int tn = (t & 15) * 4, tmg = (t >> 4) * 4;
  float acc[4][4];
  #pragma unroll
  for (int i = 0; i < 4; i++)
    #pragma unroll
    for (int j = 0; j < 4; j++) acc[i][j] = 0.f;

  for (int k = 0; k < 128; k += 4) {
    float4 a[4], w[4];
    #pragma unroll
    for (int i = 0; i < 4; i++) a[i] = *(float4*)&As[(tmg + i)*132 + k];
    #pragma unroll
    for (int j = 0; j < 4; j++) w[j] = *(float4*)&Ws[(k + j)*64 + tn];
    #pragma unroll
    for (int kk = 0; kk < 4; kk++) {
      float wv[4] = {w[kk].x, w[kk].y, w[kk].z, w[kk].w};
      float av[4] = {a[0][kk], a[1][kk], a[2][kk], a[3][kk]};
      #pragma unroll
      for (int i = 0; i < 4; i++)
        #pragma unroll
        for (int j = 0; j < 4; j++)
          acc[i][j] = fmaf(av[i], wv[j], acc[i][j]);
    }
  }
  #pragma unroll
  for (int i = 0; i < 4; i++)
    #pragma unroll
    for (int j = 0; j < 4; j++)
      atomicAdd(&Hacc[(size_t)(tmg + i)*DIM + nc + tn + j], acc[i][j]);
}

// ============================ final stage 2: Oacc += relu(Hacc+cb1) @ cw2 (K-split) =======
__global__ __launch_bounds__(256) void fgemm2_kernel(
    const float* __restrict__ Hacc, const float* __restrict__ cb1,
    const float* __restrict__ cw2, float* __restrict__ Oacc)
{
  __shared__ float As[64*132];
  __shared__ float Ws[128*64];
  int t = threadIdx.x;
  int nc = blockIdx.x * 64, kc = blockIdx.y * 128;

  #pragma unroll
  for (int p = 0; p < 8; p++) {
    int i = t + 256*p;
    int m = i >> 5, k0 = (i & 31) << 2;
    float4 v = *(const float4*)&Hacc[(size_t)m*DIM + kc + k0];
    float4 b = *(const float4*)&cb1[kc + k0];
    v.x = fmaxf(v.x + b.x, 0.f); v.y = fmaxf(v.y + b.y, 0.f);
    v.z = fmaxf(v.z + b.z, 0.f); v.w = fmaxf(v.w + b.w, 0.f);
    *(float4*)&As[m*132 + k0] = v;
  }
  #pragma unroll
  for (int p = 0; p < 8; p++) {
    int i = t + 256*p;
    int k = i >> 4, n0 = (i & 15) << 2;
    *(float4*)&Ws[k*64 + n0] = *(const float4*)&cw2[(size_t)(kc + k)*DIM + nc + n0];
  }
  __syncthreads();

  int tn = (t & 15) * 4, tmg = (t >> 4) * 4;
  float acc[4][4];
  #pragma unroll
  for (int i = 0; i < 4; i++)
    #pragma unroll
    for (int j = 0; j < 4; j++) acc[i][j] = 0.f;

  for (int k = 0; k < 128; k += 4) {
    float4 a[4], w[4];
    #pragma unroll
    for (int i = 0; i < 4; i++) a[i] = *(float4*)&As[(tmg + i)*132 + k];
    #pragma unroll
    for (int j = 0; j < 4; j++) w[j] = *(float4*)&Ws[(k + j)*64 + tn];
    #pragma unroll
    for (int kk = 0; kk < 4; kk++) {
      float wv[4] = {w[kk].x, w[kk].y, w[kk].z, w[kk].w};
      float av[4] = {a[0][kk], a[1][kk], a[2][kk], a[3][kk]};
      #pragma unroll
      for (int i = 0; i < 4; i++)
        #pragma unroll
        for (int j = 0; j < 4; j++)
          acc[i][j] = fmaf(av[i], wv[j], acc[i][j]);
    }
  }
  #pragma unroll
  for (int i = 0; i < 4; i++)
    #pragma unroll
    for (int j = 0; j < 4; j++)
      atomicAdd(&Oacc[(size_t)(tmg + i)*DIM + nc + tn + j], acc[i][j]);
}

// ============================ final stage 3: out = Oacc + cb2 =============================
__global__ __launch_bounds__(256) void fbias_kernel(
    const float* __restrict__ Oacc, const float* __restrict__ cb2,
    float* __restrict__ out)
{
  int gi = blockIdx.x * 256 + threadIdx.x;
  out[gi] = Oacc[gi] + cb2[gi & 511];
}

// ============================ launch ======================================================
extern "C" void kernel_launch(void* const* d_in, const int* in_sizes, int n_in,
                              void* d_out, int out_size, void* d_ws, size_t ws_size,
                              hipStream_t stream) {
  const float* feat   = (const float*)d_in[0];
  const int*   labels = (const int*)d_in[1];
  const float* ch_w1  = (const float*)d_in[2];
  const float* ch_b1  = (const float*)d_in[3];
  const float* ch_w2  = (const float*)d_in[4];
  const float* ch_b2  = (const float*)d_in[5];
  const float* ref_w1 = (const float*)d_in[6];
  const float* ref_b1 = (const float*)d_in[7];
  const float* ln_g   = (const float*)d_in[8];
  const float* ln_b   = (const float*)d_in[9];
  const float* ref_w2 = (const float*)d_in[10];
  const float* ref_b2 = (const float*)d_in[11];
  const float* cw1    = (const float*)d_in[12];
  const float* cb1    = (const float*)d_in[13];
  const float* cw2    = (const float*)d_in[14];
  const float* cb2    = (const float*)d_in[15];
  float* out = (float*)d_out;

  float* wsf = (float*)d_ws;
  float* off    = wsf;                 // 32768
  float* lp_all = off + 32768;         // 98304
  float* sums   = lp_all + 98304;      // 524288
  float* offW1b = sums + 524288;       // 16384
  float* Hacc   = offW1b + 16384;      // 32768
  float* Oacc   = Hacc + 32768;        // 32768
  float* Amn    = Oacc + 32768;        // 524288 (means, then H in-place)
  float* Y1     = Amn + 524288;        // 524288 (Y1, then Y2 in-place)
  float* G      = Y1 + 524288;         // variable

  size_t base_f  = (size_t)(G - wsf);                 // 1,785,856
  size_t g_hoist = (size_t)NPTS * (NLVL*HID);         // 50,331,648
  size_t g_level = (size_t)NPTS * HID;                // 16,777,216
  size_t bf16_f  = (2*(size_t)NLVL*HID*DIM + 4*(size_t)NLVL*DIM*DIM) / 2;  // 1,966,080
  size_t int_f   = 3*(size_t)NPTS + NSEG + 1040 + NSEG + 64;
  bool hoist = ws_size >= (base_f + g_hoist + bf16_f + int_f + 1024) * 4;
  size_t g_elems = hoist ? g_hoist : g_level;
  int ldg = hoist ? NLVL*HID : HID;

  bf16_t* whiT  = (bf16_t*)(G + g_elems);               // 393216
  bf16_t* wloT  = whiT + (size_t)NLVL*HID*DIM;          // 393216
  bf16_t* r1hiT = wloT + (size_t)NLVL*HID*DIM;          // 786432
  bf16_t* r1loT = r1hiT + (size_t)NLVL*DIM*DIM;
  bf16_t* r2hiT = r1loT + (size_t)NLVL*DIM*DIM;
  bf16_t* r2loT = r2hiT + (size_t)NLVL*DIM*DIM;
  int* asg     = (int*)(r2loT + (size_t)NLVL*DIM*DIM);
  int* rowlist = asg + NPTS;
  int* seglist = rowlist + NPTS;
  int* cnt_i   = seglist + NPTS;
  int* seg_st  = cnt_i + NSEG;          // 1025 used, 1040 reserved
  int* cursor  = seg_st + 1040;

  hipMemsetAsync(off, 0, NCLS*DIM*sizeof(float), stream);

  wsplit_kernel<<<NLVL*HID*DIM/256, 256, 0, stream>>>(ch_w1, whiT, wloT);
  wsplit2_kernel<<<NLVL*DIM*DIM/256, 256, 0, stream>>>(ref_w1, r1hiT, r1loT);
  wsplit2_kernel<<<NLVL*DIM*DIM/256, 256, 0, stream>>>(ref_w2, r2hiT, r2loT);

  if (hoist)
    gemm_hilo_kernel<<<dim3(NPTS/128, NLVL*HID/128), 256, 0, stream>>>(
        feat, whiT, wloT, G, ldg, 1);

  for (int l = 0; l < NLVL; l++) {
    hipMemsetAsync(cnt_i, 0, NSEG*sizeof(int), stream);
    hipMemsetAsync(sums, 0, NSEG*DIM*sizeof(float), stream);

    if (!hoist)
      gemm_hilo_kernel<<<dim3(NPTS/128, HID/128), 256, 0, stream>>>(
          feat, whiT + (size_t)l*HID*DIM, wloT + (size_t)l*HID*DIM, G, ldg, 1);

    offgemm_kernel<<<NCLS, 256, 0, stream>>>(
        off, ch_w1 + (size_t)l*DIM*HID, ch_b1 + (size_t)l*HID, offW1b);

    assign2_kernel<<<NPTS/64, 256, 0, stream>>>(
        hoist ? (G + (size_t)l*HID) : G, ldg, offW1b, labels,
        ch_w2 + (size_t)l*HID*KCL, ch_b2 + (size_t)l*KCL,
        asg, cnt_i);

    scan_kernel<<<1, 256, 0, stream>>>(cnt_i, seg_st, cursor);

    scatter_kernel<<<NPTS/256, 256, 0, stream>>>(labels, asg, cursor, rowlist, seglist);

    means3_kernel<<<dim3(NPTS/64, DIM/256), 256, 0, stream>>>(
        feat, rowlist, seglist, sums);

    meannorm_kernel<<<NSEG*DIM/256, 256, 0, stream>>>(sums, cnt_i, off, Amn);

    gemm_hilo_kernel<<<dim3(NSEG/128, DIM/128), 256, 0, stream>>>(
        Amn, r1hiT + (size_t)l*DIM*DIM, r1loT + (size_t)l*DIM*DIM, Y1, DIM, 0);

    lnrelu_kernel<<<NSEG, 256, 0, stream>>>(
        Y1, ref_b1 + (size_t)l*DIM, ln_g + (size_t)l*DIM, ln_b + (size_t)l*DIM, Amn);

    gemm_hilo_kernel<<<dim3(NSEG/128, DIM/128), 256, 0, stream>>>(
        Amn, r2hiT + (size_t)l*DIM*DIM, r2loT + (size_t)l*DIM*DIM, Y1, DIM, 0);

    protoreduce_kernel<<<NCLS*2, 256, 0, stream>>>(
        Y1, ref_b2 + (size_t)l*DIM, cnt_i, off, lp_all + (size_t)l*NCLS*DIM);
  }

  hipMemsetAsync(Hacc, 0, 2*NCLS*DIM*sizeof(float), stream);
  fgemm1_kernel<<<dim3(DIM/64, NLVL*DIM/128), 256, 0, stream>>>(lp_all, cw1, Hacc);
  fgemm2_kernel<<<dim3(DIM/64, DIM/128), 256, 0, stream>>>(Hacc, cb1, cw2, Oacc);
  fbias_kernel<<<NCLS*DIM/256, 256, 0, stream>>>(Oacc, cb2, out);
}

// Round 6
// 933.227 us; speedup vs baseline: 2.0625x; 1.1051x over previous
//
#include <hip/hip_runtime.h>

#define NPTS 65536
#define DIM  512
#define HID  256
#define KCL  16
#define NLVL 3
#define NCLS 64
#define NSEG (NCLS*KCL)
#define EPSF 1e-5f

typedef __bf16 bf16_t;
typedef bf16_t bf16x4 __attribute__((ext_vector_type(4)));
typedef bf16_t bf16x8 __attribute__((ext_vector_type(8)));
typedef float  f32x4  __attribute__((ext_vector_type(4)));

#define LDA 40   // padded LDS row stride in bf16 units

// ============================ W1 split+transpose (once): W1[l][k][j] -> [(l*256+j)][k] ====
__global__ __launch_bounds__(256) void wsplit_kernel(
    const float* __restrict__ w1, bf16_t* __restrict__ hiT, bf16_t* __restrict__ loT)
{
  int gid = blockIdx.x * 256 + threadIdx.x;   // 0..393215
  int n = gid >> 9, k = gid & 511;
  int l = n >> 8, j = n & 255;
  float v = w1[l*DIM*HID + k*HID + j];
  bf16_t h = (bf16_t)v;
  hiT[gid] = h;
  loT[gid] = (bf16_t)(v - (float)h);
}

// ============================ ref-W split+transpose, both weights in one launch ===========
__global__ __launch_bounds__(256) void wsplit2_kernel(
    const float* __restrict__ w1, const float* __restrict__ w2,
    bf16_t* __restrict__ h1, bf16_t* __restrict__ l1,
    bf16_t* __restrict__ h2, bf16_t* __restrict__ l2)
{
  const int per = NLVL*DIM*DIM;
  int gid = blockIdx.x * 256 + threadIdx.x;   // 0..2*per-1
  const float* w = (gid < per) ? w1 : w2;
  bf16_t* hh = (gid < per) ? h1 : h2;
  bf16_t* ll = (gid < per) ? l1 : l2;
  int g2 = (gid < per) ? gid : gid - per;
  int n512 = g2 >> 9, k = g2 & 511;
  int l = n512 >> 9, n = n512 & 511;
  float v = w[(size_t)l*DIM*DIM + (size_t)k*DIM + n];
  bf16_t h = (bf16_t)v;
  hh[g2] = h;
  ll[g2] = (bf16_t)(v - (float)h);
}

// ============================ big GEMM: G = feat @ W1 (128x128 tile, hi/lo 3-term) ========
__global__ __launch_bounds__(256, 2) void gemm128_kernel(
    const float* __restrict__ feat,
    const bf16_t* __restrict__ BhiT, const bf16_t* __restrict__ BloT,
    float* __restrict__ G, int ldg)
{
  __shared__ __align__(16) bf16_t Ahi[128*LDA];
  __shared__ __align__(16) bf16_t Alo[128*LDA];
  __shared__ __align__(16) bf16_t Bhi[128*LDA];
  __shared__ __align__(16) bf16_t Blo[128*LDA];

  const int t = threadIdx.x;
  const int row0 = blockIdx.x * 128, col0 = blockIdx.y * 128;
  const int w = t >> 6, lane = t & 63;
  const int wm = w & 1, wn = w >> 1;
  const int fm = lane & 15, fq = lane >> 4;

  f32x4 acc[4][4];
  #pragma unroll
  for (int i = 0; i < 4; i++)
    #pragma unroll
    for (int j = 0; j < 4; j++)
      #pragma unroll
      for (int r = 0; r < 4; r++) acc[i][j][r] = 0.f;

  for (int kc = 0; kc < DIM; kc += 32) {
    __syncthreads();
    #pragma unroll
    for (int p = 0; p < 4; p++) {
      int idx = t + 256*p;
      int r = idx >> 3, c = idx & 7;
      float4 v = *(const float4*)&feat[(size_t)(row0 + r)*DIM + kc + c*4];
      bf16x4 hi, lo;
      hi[0] = (bf16_t)v.x; lo[0] = (bf16_t)(v.x - (float)hi[0]);
      hi[1] = (bf16_t)v.y; lo[1] = (bf16_t)(v.y - (float)hi[1]);
      hi[2] = (bf16_t)v.z; lo[2] = (bf16_t)(v.z - (float)hi[2]);
      hi[3] = (bf16_t)v.w; lo[3] = (bf16_t)(v.w - (float)hi[3]);
      *(bf16x4*)&Ahi[r*LDA + c*4] = hi;
      *(bf16x4*)&Alo[r*LDA + c*4] = lo;
    }
    #pragma unroll
    for (int p = 0; p < 2; p++) {
      int idx = t + 256*p;
      int n = idx >> 2, c = idx & 3;
      *(bf16x8*)&Bhi[n*LDA + c*8] = *(const bf16x8*)&BhiT[(size_t)(col0 + n)*DIM + kc + c*8];
      *(bf16x8*)&Blo[n*LDA + c*8] = *(const bf16x8*)&BloT[(size_t)(col0 + n)*DIM + kc + c*8];
    }
    __syncthreads();

    bf16x8 ah[4], al[4], bh[4], bl[4];
    #pragma unroll
    for (int mt = 0; mt < 4; mt++) {
      int rr = (wm*64 + mt*16 + fm)*LDA + fq*8;
      ah[mt] = *(bf16x8*)&Ahi[rr];
      al[mt] = *(bf16x8*)&Alo[rr];
    }
    #pragma unroll
    for (int nt = 0; nt < 4; nt++) {
      int rr = (wn*64 + nt*16 + fm)*LDA + fq*8;
      bh[nt] = *(bf16x8*)&Bhi[rr];
      bl[nt] = *(bf16x8*)&Blo[rr];
    }
    #pragma unroll
    for (int mt = 0; mt < 4; mt++)
      #pragma unroll
      for (int nt = 0; nt < 4; nt++) {
        acc[mt][nt] = __builtin_amdgcn_mfma_f32_16x16x32_bf16(ah[mt], bh[nt], acc[mt][nt], 0, 0, 0);
        acc[mt][nt] = __builtin_amdgcn_mfma_f32_16x16x32_bf16(ah[mt], bl[nt], acc[mt][nt], 0, 0, 0);
        acc[mt][nt] = __builtin_amdgcn_mfma_f32_16x16x32_bf16(al[mt], bh[nt], acc[mt][nt], 0, 0, 0);
      }
  }

  #pragma unroll
  for (int mt = 0; mt < 4; mt++)
    #pragma unroll
    for (int nt = 0; nt < 4; nt++) {
      int col = col0 + wn*64 + nt*16 + fm;
      int rowb = row0 + wm*64 + mt*16 + fq*4;
      #pragma unroll
      for (int r = 0; r < 4; r++)
        G[(size_t)(rowb + r)*ldg + col] = acc[mt][nt][r];
    }
}

// ============================ refine GEMM: 64x64 tile, 4-term hi/lo, fused pre-ops ========
// mode 1: A[row][k] = (sums[row][k] + cnt[row]*off[cls][k]) / max(cnt,1)
// mode 2: A[row][k] = relu((Y1[row][k] + b1[k] - mS[row]) * rS[row] * g[k] + bb[k])
__global__ __launch_bounds__(256) void gemm64_kernel(
    const float* __restrict__ Asrc,
    const bf16_t* __restrict__ BhiT, const bf16_t* __restrict__ BloT,
    float* __restrict__ C, int mode,
    const int* __restrict__ cnt, const float* __restrict__ off,
    const float* __restrict__ b1, const float* __restrict__ g,
    const float* __restrict__ bb,
    const float* __restrict__ mS, const float* __restrict__ rS)
{
  __shared__ __align__(16) bf16_t Ahi[64*LDA];
  __shared__ __align__(16) bf16_t Alo[64*LDA];
  __shared__ __align__(16) bf16_t Bhi[64*LDA];
  __shared__ __align__(16) bf16_t Blo[64*LDA];
  __shared__ float rm[64], rr_[64];

  const int t = threadIdx.x;
  const int row0 = blockIdx.x * 64, col0 = blockIdx.y * 64;
  const int w = t >> 6, lane = t & 63;
  const int wm = w & 1, wn = w >> 1;
  const int fm = lane & 15, fq = lane >> 4;

  if (t < 64) {
    if (mode == 1) {
      int n = cnt[row0 + t];
      rm[t] = (float)n;
      rr_[t] = 1.f / fmaxf((float)n, 1.f);
    } else {
      rm[t] = mS[row0 + t];
      rr_[t] = rS[row0 + t];
    }
  }

  f32x4 acc[2][2];
  #pragma unroll
  for (int i = 0; i < 2; i++)
    #pragma unroll
    for (int j = 0; j < 2; j++)
      #pragma unroll
      for (int r = 0; r < 4; r++) acc[i][j][r] = 0.f;

  for (int kc = 0; kc < DIM; kc += 32) {
    __syncthreads();
    #pragma unroll
    for (int p = 0; p < 2; p++) {
      int idx = t + 256*p;
      int r = idx >> 3, c = idx & 7;
      float4 v = *(const float4*)&Asrc[(size_t)(row0 + r)*DIM + kc + c*4];
      if (mode == 1) {
        int cls = (row0 + r) >> 4;
        float4 o = *(const float4*)&off[(size_t)cls*DIM + kc + c*4];
        float n = rm[r], inv = rr_[r];
        v.x = (v.x + n*o.x) * inv; v.y = (v.y + n*o.y) * inv;
        v.z = (v.z + n*o.z) * inv; v.w = (v.w + n*o.w) * inv;
      } else {
        float4 B1 = *(const float4*)&b1[kc + c*4];
        float4 G4 = *(const float4*)&g[kc + c*4];
        float4 BB = *(const float4*)&bb[kc + c*4];
        float m = rm[r], rs = rr_[r];
        v.x = fmaxf((v.x + B1.x - m)*rs*G4.x + BB.x, 0.f);
        v.y = fmaxf((v.y + B1.y - m)*rs*G4.y + BB.y, 0.f);
        v.z = fmaxf((v.z + B1.z - m)*rs*G4.z + BB.z, 0.f);
        v.w = fmaxf((v.w + B1.w - m)*rs*G4.w + BB.w, 0.f);
      }
      bf16x4 hi, lo;
      hi[0] = (bf16_t)v.x; lo[0] = (bf16_t)(v.x - (float)hi[0]);
      hi[1] = (bf16_t)v.y; lo[1] = (bf16_t)(v.y - (float)hi[1]);
      hi[2] = (bf16_t)v.z; lo[2] = (bf16_t)(v.z - (float)hi[2]);
      hi[3] = (bf16_t)v.w; lo[3] = (bf16_t)(v.w - (float)hi[3]);
      *(bf16x4*)&Ahi[r*LDA + c*4] = hi;
      *(bf16x4*)&Alo[r*LDA + c*4] = lo;
    }
    {
      int n = t >> 2, kof = (t & 3)*8;
      *(bf16x8*)&Bhi[n*LDA + kof] = *(const bf16x8*)&BhiT[(size_t)(col0 + n)*DIM + kc + kof];
      *(bf16x8*)&Blo[n*LDA + kof] = *(const bf16x8*)&BloT[(size_t)(col0 + n)*DIM + kc + kof];
    }
    __syncthreads();

    bf16x8 ah[2], al[2], bh[2], bl[2];
    #pragma unroll
    for (int mt = 0; mt < 2; mt++) {
      int idx = (wm*32 + mt*16 + fm)*LDA + fq*8;
      ah[mt] = *(bf16x8*)&Ahi[idx];
      al[mt] = *(bf16x8*)&Alo[idx];
    }
    #pragma unroll
    for (int nt = 0; nt < 2; nt++) {
      int idx = (wn*32 + nt*16 + fm)*LDA + fq*8;
      bh[nt] = *(bf16x8*)&Bhi[idx];
      bl[nt] = *(bf16x8*)&Blo[idx];
    }
    #pragma unroll
    for (int mt = 0; mt < 2; mt++)
      #pragma unroll
      for (int nt = 0; nt < 2; nt++) {
        acc[mt][nt] = __builtin_amdgcn_mfma_f32_16x16x32_bf16(ah[mt], bh[nt], acc[mt][nt], 0, 0, 0);
        acc[mt][nt] = __builtin_amdgcn_mfma_f32_16x16x32_bf16(ah[mt], bl[nt], acc[mt][nt], 0, 0, 0);
        acc[mt][nt] = __builtin_amdgcn_mfma_f32_16x16x32_bf16(al[mt], bh[nt], acc[mt][nt], 0, 0, 0);
        acc[mt][nt] = __builtin_amdgcn_mfma_f32_16x16x32_bf16(al[mt], bl[nt], acc[mt][nt], 0, 0, 0);
      }
  }

  #pragma unroll
  for (int mt = 0; mt < 2; mt++)
    #pragma unroll
    for (int nt = 0; nt < 2; nt++) {
      int col = col0 + wn*32 + nt*16 + fm;
      int rowb = row0 + wm*32 + mt*16 + fq*4;
      #pragma unroll
      for (int r = 0; r < 4; r++)
        C[(size_t)(rowb + r)*DIM + col] = acc[mt][nt][r];
    }
}

// ============================ LN stats of (Y1 + b1) per row ===============================
__global__ __launch_bounds__(256) void lnstats_kernel(
    const float* __restrict__ Y1, const float* __restrict__ b1,
    float* __restrict__ mS, float* __restrict__ rS)
{
  int r = blockIdx.x, t = threadIdx.x;
  float x0 = Y1[(size_t)r*DIM + t]       + b1[t];
  float x1 = Y1[(size_t)r*DIM + t + 256] + b1[t + 256];
  float s1 = x0 + x1, s2 = x0*x0 + x1*x1;
  #pragma unroll
  for (int ofs = 32; ofs > 0; ofs >>= 1) {
    s1 += __shfl_xor(s1, ofs);
    s2 += __shfl_xor(s2, ofs);
  }
  __shared__ float r1[4], r2[4];
  int lane = t & 63, w = t >> 6;
  if (lane == 0) { r1[w] = s1; r2[w] = s2; }
  __syncthreads();
  if (t == 0) {
    s1 = r1[0] + r1[1] + r1[2] + r1[3];
    s2 = r2[0] + r2[1] + r2[2] + r2[3];
    float m = s1 * (1.f/512.f);
    float var = s2 * (1.f/512.f) - m*m;
    mS[r] = m;
    rS[r] = rsqrtf(var + EPSF);
  }
}

// ============================ offW1b[c][j] = off[c]@W1_l[:,j] + b1[j] (l=0 handled by ldo=0)
// fused: lp[c] = mean over non-empty k of Y2 + b2; off += lp; then next-level offgemm.
__global__ __launch_bounds__(256) void protoOffgemm_kernel(
    const float* __restrict__ Y2, const float* __restrict__ b2,
    const int* __restrict__ cnt, float* __restrict__ off, float* __restrict__ lp_out,
    const float* __restrict__ w1next, const float* __restrict__ b1next,
    float* __restrict__ offW1b)
{
  __shared__ float offs[DIM];
  int c = blockIdx.x, t = threadIdx.x;
  int nes = 0;
  #pragma unroll
  for (int k = 0; k < KCL; k++) nes += (cnt[c*KCL + k] > 0);
  float inv = 1.f / (float)nes;
  #pragma unroll
  for (int h = 0; h < 2; h++) {
    int d = t + h*256;
    float s = 0.f;
    #pragma unroll
    for (int k = 0; k < KCL; k++)
      if (cnt[c*KCL + k] > 0) s += Y2[(size_t)(c*KCL + k)*DIM + d];
    float lp = s * inv + b2[d];
    lp_out[c*DIM + d] = lp;
    float on = off[c*DIM + d] + lp;
    off[c*DIM + d] = on;
    offs[d] = on;
  }
  if (w1next == nullptr) return;
  __syncthreads();
  float a = 0.f;
  #pragma unroll 4
  for (int d = 0; d < DIM; d++)
    a = fmaf(offs[d], w1next[d*HID + t], a);
  offW1b[c*HID + t] = a + b1next[t];
}

// ============================ assign2: h=relu(Gl+offsrc[lab*ldo]); logits=hW2+b2; argmax ==
__global__ __launch_bounds__(256) void assign2_kernel(
    const float* __restrict__ Gl, int ldg,
    const float* __restrict__ offsrc, int ldo,
    const int* __restrict__ labels,
    const float* __restrict__ w2, const float* __restrict__ pb2,
    int* __restrict__ asg, int* __restrict__ cnt)
{
  __shared__ float W2s[256*17];
  __shared__ int   labs[64];
  const int tid = threadIdx.x;
  const int tx = tid & 15, ty = tid >> 4;
  const int row0 = blockIdx.x * 64;

  if (tid < 64) labs[tid] = labels[row0 + tid];
  for (int idx = tid; idx < HID*KCL; idx += 256)
    W2s[(idx >> 4)*17 + (idx & 15)] = w2[idx];
  __syncthreads();

  float h[4][16];
  #pragma unroll
  for (int i = 0; i < 4; i++) {
    int r = ty*4 + i, row = row0 + r, lab = labs[r];
    #pragma unroll
    for (int q = 0; q < 4; q++) {
      float4 g = *(const float4*)&Gl[(size_t)row*ldg + q*64 + tx*4];
      float4 o = *(const float4*)&offsrc[(size_t)lab*ldo + q*64 + tx*4];
      h[i][q*4+0] = fmaxf(g.x + o.x, 0.f);
      h[i][q*4+1] = fmaxf(g.y + o.y, 0.f);
      h[i][q*4+2] = fmaxf(g.z + o.z, 0.f);
      h[i][q*4+3] = fmaxf(g.w + o.w, 0.f);
    }
  }

  float part[4][16];
  #pragma unroll
  for (int i = 0; i < 4; i++)
    #pragma unroll
    for (int k2 = 0; k2 < 16; k2++) part[i][k2] = 0.f;

  #pragma unroll
  for (int qi = 0; qi < 16; qi++) {
    int j = (qi >> 2)*64 + tx*4 + (qi & 3);
    float w2r[16];
    #pragma unroll
    for (int s = 0; s < 16; s++) w2r[s] = W2s[j*17 + s];
    #pragma unroll
    for (int i = 0; i < 4; i++)
      #pragma unroll
      for (int k2 = 0; k2 < 16; k2++)
        part[i][k2] = fmaf(h[i][qi], w2r[k2], part[i][k2]);
  }

  #pragma unroll
  for (int ofs = 8; ofs > 0; ofs >>= 1)
    #pragma unroll
    for (int i = 0; i < 4; i++)
      #pragma unroll
      for (int k2 = 0; k2 < 16; k2++)
        part[i][k2] += __shfl_xor(part[i][k2], ofs, 16);

  if (tx == 0) {
    #pragma unroll
    for (int i = 0; i < 4; i++) {
      int r = ty*4 + i;
      float best = part[i][0] + pb2[0];
      int bi = 0;
      #pragma unroll
      for (int k2 = 1; k2 < 16; k2++) {
        float v = part[i][k2] + pb2[k2];
        if (v > best) { best = v; bi = k2; }
      }
      asg[row0 + r] = bi;
      atomicAdd(&cnt[labs[r]*KCL + bi], 1);
    }
  }
}

// ============================ exclusive scan (shuffle-based) ==============================
__global__ void scan_kernel(const int* __restrict__ cnt, int* __restrict__ seg_st,
                            int* __restrict__ cursor)
{
  int t = threadIdx.x;
  int4 v = *(const int4*)&cnt[t*4];
  int a0 = v.x, a1 = v.x + v.y, a2 = a1 + v.z, tot = a2 + v.w;
  int lane = t & 63, w = t >> 6;
  int sc = tot;
  #pragma unroll
  for (int ofs = 1; ofs < 64; ofs <<= 1) {
    int u = __shfl_up(sc, ofs);
    if (lane >= ofs) sc += u;
  }
  __shared__ int wt[4];
  if (lane == 63) wt[w] = sc;
  __syncthreads();
  int base = 0;
  #pragma unroll
  for (int i = 0; i < 4; i++) if (i < w) base += wt[i];
  int excl = base + sc - tot;
  seg_st[t*4 + 1] = excl + a0;
  seg_st[t*4 + 2] = excl + a1;
  seg_st[t*4 + 3] = excl + a2;
  seg_st[t*4 + 4] = excl + tot;
  if (t == 0) seg_st[0] = 0;
  int4 cur = {excl, excl + a0, excl + a1, excl + a2};
  *(int4*)&cursor[t*4] = cur;
}

// ============================ scatter rows into per-segment sorted lists ==================
__global__ __launch_bounds__(256) void scatter_kernel(
    const int* __restrict__ labels, const int* __restrict__ asg,
    int* __restrict__ cursor, int* __restrict__ rowlist, int* __restrict__ seglist)
{
  int i = blockIdx.x * 256 + threadIdx.x;
  int seg = labels[i]*KCL + asg[i];
  int pos = atomicAdd(&cursor[seg], 1);
  rowlist[pos] = i;
  seglist[pos] = seg;
}

// ============================ balanced segmented sums over sorted rowlist =================
__global__ __launch_bounds__(256) void means3_kernel(
    const float* __restrict__ feat, const int* __restrict__ rowlist,
    const int* __restrict__ seglist, float* __restrict__ sums)
{
  __shared__ int rows[64];
  __shared__ int segs[65];
  int t = threadIdx.x;
  int i0 = blockIdx.x * 64;
  int col = blockIdx.y * 256 + t;
  if (t < 64) { rows[t] = rowlist[i0 + t]; segs[t] = seglist[i0 + t]; }
  if (t == 64) segs[64] = -1;
  __syncthreads();
  float acc = 0.f;
  for (int base = 0; base < 64; base += 16) {
    float v[16];
    #pragma unroll
    for (int j = 0; j < 16; j++)
      v[j] = feat[(size_t)rows[base + j]*DIM + col];
    #pragma unroll
    for (int j = 0; j < 16; j++) {
      acc += v[j];
      if (segs[base + j] != segs[base + j + 1]) {
        atomicAdd(&sums[(size_t)segs[base + j]*DIM + col], acc);
        acc = 0.f;
      }
    }
  }
}

// ============================ final stage 1: Hacc += comb[64x1536] @ cw1 (K-split) ========
__global__ __launch_bounds__(256) void fgemm1_kernel(
    const float* __restrict__ lp_all, const float* __restrict__ cw1,
    float* __restrict__ Hacc)
{
  __shared__ float As[64*132];
  __shared__ float Ws[128*64];
  int t = threadIdx.x;
  int nc = blockIdx.x * 64, kc = blockIdx.y * 128;

  #pragma unroll
  for (int p = 0; p < 8; p++) {
    int i = t + 256*p;
    int m = i >> 5, k0 = (i & 31) << 2;
    int k = kc + k0;
    int l = k >> 9, d = k & 511;
    *(float4*)&As[m*132 + k0] = *(const float4*)&lp_all[(size_t)(l*NCLS + m)*DIM + d];
  }
  #pragma unroll
  for (int p = 0; p < 8; p++) {
    int i = t + 256*p;
    int k = i >> 4, n0 = (i & 15) << 2;
    *(float4*)&Ws[k*64 + n0] = *(const float4*)&cw1[(size_t)(kc + k)*DIM + nc + n0];
  }
  __syncthreads();

  int tn = (t & 15) * 4, tmg = (t >> 4) * 4;
  float acc[4][4];
  #pragma unroll
  for (int i = 0; i < 4; i++)
    #pragma unroll
    for (int j = 0; j < 4; j++) acc[i][j] = 0.f;

  for (int k = 0; k < 128; k += 4) {
    float4 a[4], w[4];
    #pragma unroll
    for (int i = 0; i < 4; i++) a[i] = *(float4*)&As[(tmg + i)*132 + k];
    #pragma unroll
    for (int j = 0; j < 4; j++) w[j] = *(float4*)&Ws[(k + j)*64 + tn];
    #pragma unroll
    for (int kk = 0; kk < 4; kk++) {
      float wv[4] = {w[kk].x, w[kk].y, w[kk].z, w[kk].w};
      float av[4] = {a[0][kk], a[1][kk], a[2][kk], a[3][kk]};
      #pragma unroll
      for (int i = 0; i < 4; i++)
        #pragma unroll
        for (int j = 0; j < 4; j++)
          acc[i][j] = fmaf(av[i], wv[j], acc[i][j]);
    }
  }
  #pragma unroll
  for (int i = 0; i < 4; i++)
    #pragma unroll
    for (int j = 0; j < 4; j++)
      atomicAdd(&Hacc[(size_t)(tmg + i)*DIM + nc + tn + j], acc[i][j]);
}

// ============================ final stage 2: Oacc += relu(Hacc+cb1) @ cw2 (K-split) =======
__global__ __launch_bounds__(256) void fgemm2_kernel(
    const float* __restrict__ Hacc, const float* __restrict__ cb1,
    const float* __restrict__ cw2, float* __restrict__ Oacc)
{
  __shared__ float As[64*132];
  __shared__ float Ws[128*64];
  int t = threadIdx.x;
  int nc = blockIdx.x * 64, kc = blockIdx.y * 128;

  #pragma unroll
  for (int p = 0; p < 8; p++) {
    int i = t + 256*p;
    int m = i >> 5, k0 = (i & 31) << 2;
    float4 v = *(const float4*)&Hacc[(size_t)m*DIM + kc + k0];
    float4 b = *(const float4*)&cb1[kc + k0];
    v.x = fmaxf(v.x + b.x, 0.f); v.y = fmaxf(v.y + b.y, 0.f);
    v.z = fmaxf(v.z + b.z, 0.f); v.w = fmaxf(v.w + b.w, 0.f);
    *(float4*)&As[m*132 + k0] = v;
  }
  #pragma unroll
  for (int p = 0; p < 8; p++) {
    int i = t + 256*p;
    int k = i >> 4, n0 = (i & 15) << 2;
    *(float4*)&Ws[k*64 + n0] = *(const float4*)&cw2[(size_t)(kc + k)*DIM + nc + n0];
  }
  __syncthreads();

  int tn = (t & 15) * 4, tmg = (t >> 4) * 4;
  float acc[4][4];
  #pragma unroll
  for (int i = 0; i < 4; i++)
    #pragma unroll
    for (int j = 0; j < 4; j++) acc[i][j] = 0.f;

  for (int k = 0; k < 128; k += 4) {
    float4 a[4], w[4];
    #pragma unroll
    for (int i = 0; i < 4; i++) a[i] = *(float4*)&As[(tmg + i)*132 + k];
    #pragma unroll
    for (int j = 0; j < 4; j++) w[j] = *(float4*)&Ws[(k + j)*64 + tn];
    #pragma unroll
    for (int kk = 0; kk < 4; kk++) {
      float wv[4] = {w[kk].x, w[kk].y, w[kk].z, w[kk].w};
      float av[4] = {a[0][kk], a[1][kk], a[2][kk], a[3][kk]};
      #pragma unroll
      for (int i = 0; i < 4; i++)
        #pragma unroll
        for (int j = 0; j < 4; j++)
          acc[i][j] = fmaf(av[i], wv[j], acc[i][j]);
    }
  }
  #pragma unroll
  for (int i = 0; i < 4; i++)
    #pragma unroll
    for (int j = 0; j < 4; j++)
      atomicAdd(&Oacc[(size_t)(tmg + i)*DIM + nc + tn + j], acc[i][j]);
}

// ============================ final stage 3: out = Oacc + cb2 =============================
__global__ __launch_bounds__(256) void fbias_kernel(
    const float* __restrict__ Oacc, const float* __restrict__ cb2,
    float* __restrict__ out)
{
  int gi = blockIdx.x * 256 + threadIdx.x;
  out[gi] = Oacc[gi] + cb2[gi & 511];
}

// ============================ launch ======================================================
extern "C" void kernel_launch(void* const* d_in, const int* in_sizes, int n_in,
                              void* d_out, int out_size, void* d_ws, size_t ws_size,
                              hipStream_t stream) {
  const float* feat   = (const float*)d_in[0];
  const int*   labels = (const int*)d_in[1];
  const float* ch_w1  = (const float*)d_in[2];
  const float* ch_b1  = (const float*)d_in[3];
  const float* ch_w2  = (const float*)d_in[4];
  const float* ch_b2  = (const float*)d_in[5];
  const float* ref_w1 = (const float*)d_in[6];
  const float* ref_b1 = (const float*)d_in[7];
  const float* ln_g   = (const float*)d_in[8];
  const float* ln_b   = (const float*)d_in[9];
  const float* ref_w2 = (const float*)d_in[10];
  const float* ref_b2 = (const float*)d_in[11];
  const float* cw1    = (const float*)d_in[12];
  const float* cb1    = (const float*)d_in[13];
  const float* cw2    = (const float*)d_in[14];
  const float* cb2    = (const float*)d_in[15];
  float* out = (float*)d_out;

  float* wsf = (float*)d_ws;
  float* off    = wsf;                 // 32768
  float* lp_all = off + 32768;         // 98304
  float* sums   = lp_all + 98304;      // 524288
  int*   cnt_i  = (int*)(sums + 524288); // 1024 (adjacent to sums: single memset)
  float* offW1b = sums + 524288 + 1024; // 16384
  float* Hacc   = offW1b + 16384;      // 32768
  float* Oacc   = Hacc + 32768;        // 32768
  float* Y1     = Oacc + 32768;        // 524288
  float* Y2     = Y1 + 524288;         // 524288
  float* mS     = Y2 + 524288;         // 1024
  float* rS     = mS + 1024;           // 1024
  float* G      = rS + 1024;           // variable

  size_t base_f  = (size_t)(G - wsf);
  size_t g_hoist = (size_t)NPTS * (NLVL*HID);
  size_t g_level = (size_t)NPTS * HID;
  size_t bf16_f  = ((size_t)2*NLVL*HID*DIM + (size_t)4*NLVL*DIM*DIM) / 2;
  size_t int_f   = 3*(size_t)NPTS + 1040 + NSEG + 64;
  bool hoist = ws_size >= (base_f + g_hoist + bf16_f + int_f + 1024) * 4;
  size_t g_elems = hoist ? g_hoist : g_level;
  int ldg = hoist ? NLVL*HID : HID;

  bf16_t* whiT  = (bf16_t*)(G + g_elems);
  bf16_t* wloT  = whiT + (size_t)NLVL*HID*DIM;
  bf16_t* r1hiT = wloT + (size_t)NLVL*HID*DIM;
  bf16_t* r1loT = r1hiT + (size_t)NLVL*DIM*DIM;
  bf16_t* r2hiT = r1loT + (size_t)NLVL*DIM*DIM;
  bf16_t* r2loT = r2hiT + (size_t)NLVL*DIM*DIM;
  int* asg     = (int*)(r2loT + (size_t)NLVL*DIM*DIM);
  int* rowlist = asg + NPTS;
  int* seglist = rowlist + NPTS;
  int* seg_st  = seglist + NPTS;       // 1025 used, 1040 reserved
  int* cursor  = seg_st + 1040;

  hipMemsetAsync(off, 0, NCLS*DIM*sizeof(float), stream);

  wsplit_kernel<<<NLVL*HID*DIM/256, 256, 0, stream>>>(ch_w1, whiT, wloT);
  wsplit2_kernel<<<2*NLVL*DIM*DIM/256, 256, 0, stream>>>(
      ref_w1, ref_w2, r1hiT, r1loT, r2hiT, r2loT);

  if (hoist)
    gemm128_kernel<<<dim3(NPTS/128, NLVL*HID/128), 256, 0, stream>>>(
        feat, whiT, wloT, G, ldg);

  for (int l = 0; l < NLVL; l++) {
    hipMemsetAsync(sums, 0, (NSEG*DIM + NSEG)*sizeof(float), stream);  // sums + cnt_i

    if (!hoist)
      gemm128_kernel<<<dim3(NPTS/128, HID/128), 256, 0, stream>>>(
          feat, whiT + (size_t)l*HID*DIM, wloT + (size_t)l*HID*DIM, G, ldg);

    // l=0: off==0 -> offW1b[c] == b1 for all c -> read b1 with row-stride 0
    const float* offsrc = (l == 0) ? ch_b1 : offW1b;
    int ldo = (l == 0) ? 0 : HID;

    assign2_kernel<<<NPTS/64, 256, 0, stream>>>(
        hoist ? (G + (size_t)l*HID) : G, ldg, offsrc, ldo, labels,
        ch_w2 + (size_t)l*HID*KCL, ch_b2 + (size_t)l*KCL,
        asg, cnt_i);

    scan_kernel<<<1, 256, 0, stream>>>(cnt_i, seg_st, cursor);

    scatter_kernel<<<NPTS/256, 256, 0, stream>>>(labels, asg, cursor, rowlist, seglist);

    means3_kernel<<<dim3(NPTS/64, DIM/256), 256, 0, stream>>>(
        feat, rowlist, seglist, sums);

    // refine: Y1 = meannorm(sums) @ ref_w1   (meannorm fused into staging)
    gemm64_kernel<<<dim3(NSEG/64, DIM/64), 256, 0, stream>>>(
        sums, r1hiT + (size_t)l*DIM*DIM, r1loT + (size_t)l*DIM*DIM, Y1, 1,
        cnt_i, off, nullptr, nullptr, nullptr, nullptr, nullptr);

    lnstats_kernel<<<NSEG, 256, 0, stream>>>(
        Y1, ref_b1 + (size_t)l*DIM, mS, rS);

    // Y2 = relu(LN(Y1+b1)*g+b) @ ref_w2     (LN-apply fused into staging)
    gemm64_kernel<<<dim3(NSEG/64, DIM/64), 256, 0, stream>>>(
        Y1, r2hiT + (size_t)l*DIM*DIM, r2loT + (size_t)l*DIM*DIM, Y2, 2,
        nullptr, nullptr, ref_b1 + (size_t)l*DIM,
        ln_g + (size_t)l*DIM, ln_b + (size_t)l*DIM, mS, rS);

    // lp + off update + next level's offW1b (fused); l=2 skips the offgemm part
    protoOffgemm_kernel<<<NCLS, 256, 0, stream>>>(
        Y2, ref_b2 + (size_t)l*DIM, cnt_i, off, lp_all + (size_t)l*NCLS*DIM,
        (l < NLVL-1) ? (ch_w1 + (size_t)(l+1)*DIM*HID) : nullptr,
        (l < NLVL-1) ? (ch_b1 + (size_t)(l+1)*HID) : nullptr,
        offW1b);
  }

  hipMemsetAsync(Hacc, 0, 2*NCLS*DIM*sizeof(float), stream);
  fgemm1_kernel<<<dim3(DIM/64, NLVL*DIM/128), 256, 0, stream>>>(lp_all, cw1, Hacc);
  fgemm2_kernel<<<dim3(DIM/64, DIM/128), 256, 0, stream>>>(Hacc, cb1, cw2, Oacc);
  fbias_kernel<<<NCLS*DIM/256, 256, 0, stream>>>(Oacc, cb2, out);
}